// Round 16
// baseline (691.029 us; speedup 1.0000x reference)
//
#include <hip/hip_runtime.h>
#include <hip/hip_bf16.h>

typedef __hip_bfloat16 bf16;
typedef _Float16 f16;
typedef __attribute__((ext_vector_type(8))) _Float16 f16x8;
typedef __attribute__((ext_vector_type(4))) float f32x4;

// ---------------------------------------------------------------- dtype detector (wave-parallel)
__global__ void detect_k(const unsigned short* __restrict__ xh, int* __restrict__ flags)
{
  const int t = threadIdx.x;   // 64
  int w = 0;
  for (int i = t; i < 512; i += 64) {
    const int e = (xh[i] >> 7) & 0xFF;
    if (e == 0xFF || e >= 0x88) ++w;
  }
  #pragma unroll
  for (int msk = 1; msk < 64; msk <<= 1) w += __shfl_xor(w, msk);
  if (t == 0) flags[0] = (w > 32) ? 1 : 0;
}

// ---------------------------------------------------------------- batched input->fp32 convert
#define NSEG 33
struct CvtDesc {
  const void* src[NSEG];
  unsigned dstOff[NSEG];
  unsigned n[NSEG];
};
__global__ __launch_bounds__(256) void cvtall_k(
    CvtDesc d, float* __restrict__ P, const int* __restrict__ flags)
{
  const int s = blockIdx.y;
  const unsigned n = d.n[s];
  const int fp32 = flags[0];
  float* dst = P + d.dstOff[s];
  const unsigned stride = gridDim.x * 256u;
  if (fp32) {
    const float* src = (const float*)d.src[s];
    for (unsigned i = blockIdx.x * 256u + threadIdx.x; i < n; i += stride) dst[i] = src[i];
  } else {
    const bf16* src = (const bf16*)d.src[s];
    for (unsigned i = blockIdx.x * 256u + threadIdx.x; i < n; i += stride)
      dst[i] = __bfloat162float(src[i]);
  }
}

// ---------------------------------------------------------------- conv weight prep
__global__ __launch_bounds__(256) void prepw_k(
    const float* __restrict__ ucw, const float* __restrict__ utw, const float* __restrict__ ocw,
    f16* __restrict__ wf3, f16* __restrict__ wt, f16* __restrict__ wocp)
{
  const int n1 = 3 * 9 * 65536;
  const int n2 = 3 * 4 * 65536;
  const int n3 = 9 * 16 * 256;
  for (int i = blockIdx.x * 256 + threadIdx.x; i < n1 + n2 + n3; i += gridDim.x * 256) {
    if (i < n1) {
      const int st = i / 589824, r = i % 589824;
      const int kk = r / 65536, rr = r % 65536;
      const int co = rr >> 8, ci = rr & 255;
      wf3[i] = (f16)ucw[(((size_t)st * 256 + co) * 256 + ci) * 9 + kk];
    } else if (i < n1 + n2) {
      const int j = i - n1;
      const int st = j / 262144, r = j % 262144;
      const int ij = r / 65536, rr = r % 65536;
      const int co = rr >> 8, ci = rr & 255;
      wt[j] = (f16)utw[(((size_t)st * 256 + ci) * 256 + co) * 4 + ij];
    } else {
      const int j = i - n1 - n2;
      const int tap = j >> 12, rem = j & 4095;
      const int co = rem >> 8, ci = rem & 255;
      wocp[j] = (co < 3) ? (f16)ocw[(((size_t)co * 256) + ci) * 9 + tap] : (f16)0.f;
    }
  }
}

// ---------------------------------------------------------------- MFMA GEMM 64x64 tile, 4 waves
template<bool TRB, int ACT>
__global__ __launch_bounds__(256) void gemm64_k(
    const float* __restrict__ A, const float* __restrict__ B,
    const float* __restrict__ bias, const float* __restrict__ res,
    float* __restrict__ C, int M, int N, int K)
{
  const int m0 = blockIdx.y << 6, n0 = blockIdx.x << 6;
  const int t = threadIdx.x;
  const int lane = t & 63, wv = t >> 6;
  const int wm = wv >> 1, wn = wv & 1;
  const int frow = lane & 15, kg = lane >> 4;
  __shared__ f16 As[64][40];
  __shared__ f16 Bs[64][40];
  f32x4 acc[2][2];
  #pragma unroll
  for (int i = 0; i < 2; ++i)
    #pragma unroll
    for (int j = 0; j < 2; ++j) acc[i][j] = (f32x4){0.f, 0.f, 0.f, 0.f};

  for (int k0 = 0; k0 < K; k0 += 32) {
    __syncthreads();
    {
      const int row = t >> 2, kh = (t & 3) << 3;
      const float* ap = A + (size_t)(m0 + row) * K + k0 + kh;
      #pragma unroll
      for (int j = 0; j < 8; ++j) As[row][kh + j] = (f16)ap[j];
    }
    if (TRB) {
      const int row = t >> 2, kh = (t & 3) << 3;
      const float* bp = B + (size_t)(n0 + row) * K + k0 + kh;
      #pragma unroll
      for (int j = 0; j < 8; ++j) Bs[row][kh + j] = (f16)bp[j];
    } else {
      #pragma unroll
      for (int i2 = 0; i2 < 8; ++i2) {
        const int i = i2 * 256 + t;
        const int n = i & 63, kk = i >> 6;
        Bs[n][kk] = (f16)B[(size_t)(k0 + kk) * N + n0 + n];
      }
    }
    __syncthreads();
    f16x8 af[2], bf[2];
    #pragma unroll
    for (int fm = 0; fm < 2; ++fm)
      af[fm] = *(const f16x8*)&As[wm * 32 + fm * 16 + frow][kg * 8];
    #pragma unroll
    for (int fn = 0; fn < 2; ++fn)
      bf[fn] = *(const f16x8*)&Bs[wn * 32 + fn * 16 + frow][kg * 8];
    #pragma unroll
    for (int fm = 0; fm < 2; ++fm)
      #pragma unroll
      for (int fn = 0; fn < 2; ++fn)
        acc[fm][fn] = __builtin_amdgcn_mfma_f32_16x16x32_f16(af[fm], bf[fn], acc[fm][fn], 0, 0, 0);
  }
  #pragma unroll
  for (int fn = 0; fn < 2; ++fn) {
    const int col = n0 + wn * 32 + fn * 16 + frow;
    const float bv = bias ? bias[col] : 0.f;
    #pragma unroll
    for (int fm = 0; fm < 2; ++fm)
      #pragma unroll
      for (int r = 0; r < 4; ++r) {
        const int row = m0 + wm * 32 + fm * 16 + kg * 4 + r;
        float v = acc[fm][fn][r] + bv;
        if (ACT == 1) v = 0.5f * v * (1.0f + erff(v * 0.70710678118654752f));
        if (res) v += res[(size_t)row * N + col];
        C[(size_t)row * N + col] = v;
      }
  }
}

// ---------------------------------------------------------------- LayerNorm (row len 256, shfl reduce)
__global__ __launch_bounds__(256) void ln_k(
    const float* __restrict__ in, float* __restrict__ out,
    const float* __restrict__ g, const float* __restrict__ b)
{
  const int row = blockIdx.x, t = threadIdx.x;
  __shared__ float ws1[4], ws2[4];
  const float x = in[(size_t)row * 256 + t];
  float v = x;
  #pragma unroll
  for (int msk = 1; msk < 64; msk <<= 1) v += __shfl_xor(v, msk);
  if ((t & 63) == 0) ws1[t >> 6] = v;
  __syncthreads();
  const float m = (ws1[0] + ws1[1] + ws1[2] + ws1[3]) * (1.0f / 256.0f);
  const float d = x - m;
  float v2 = d * d;
  #pragma unroll
  for (int msk = 1; msk < 64; msk <<= 1) v2 += __shfl_xor(v2, msk);
  if ((t & 63) == 0) ws2[t >> 6] = v2;
  __syncthreads();
  const float rstd = rsqrtf((ws2[0] + ws2[1] + ws2[2] + ws2[3]) * (1.0f / 256.0f) + 1e-5f);
  out[(size_t)row * 256 + t] = d * rstd * g[t] + b[t];
}

// ---------------------------------------------------------------- L2 normalize rows (shfl reduce)
__global__ __launch_bounds__(256) void l2n_k(float* __restrict__ x)
{
  const int row = blockIdx.x, t = threadIdx.x;
  __shared__ float ws[4];
  const float v = x[(size_t)row * 256 + t];
  float s = v * v;
  #pragma unroll
  for (int msk = 1; msk < 64; msk <<= 1) s += __shfl_xor(s, msk);
  if ((t & 63) == 0) ws[t >> 6] = s;
  __syncthreads();
  x[(size_t)row * 256 + t] = v * rsqrtf(ws[0] + ws[1] + ws[2] + ws[3]);
}

// ---------------------------------------------------------------- pos hidden (elementwise)
__global__ __launch_bounds__(256) void posh_k(
    const int* __restrict__ pc, const float* __restrict__ w1, const float* __restrict__ b1,
    float* __restrict__ hid)
{
  const int n = blockIdx.x, t = threadIdx.x;
  const int wide = (pc[3] == 0);
  const int sv = wide ? pc[4 * n] : pc[2 * n];
  const int cv = wide ? pc[4 * n + 2] : pc[2 * n + 1];
  const float hv = (float)sv * w1[t] + (float)cv * w1[256 + t] + b1[t];
  hid[(size_t)n * 256 + t] = hv > 0.0f ? hv : 0.0f;
}

// ---------------------------------------------------------------- assemble x = [proj+pos ; cls]
__global__ __launch_bounds__(256) void assemble_k(
    const float* __restrict__ proj, const float* __restrict__ pos,
    const float* __restrict__ cls, float* __restrict__ xb)
{
  const int row = blockIdx.x;
  const int b = row / 896, n = row % 896, t = threadIdx.x;
  float v;
  if (n < 640) v = proj[((size_t)b * 640 + n) * 256 + t] + pos[n * 256 + t];
  else         v = cls[(n - 640) * 256 + t];
  xb[(size_t)row * 256 + t] = v;
}

// ---------------------------------------------------------------- MFMA flash attention
__global__ __launch_bounds__(128) void attnm_k(
    const float* __restrict__ qkv, float* __restrict__ out)
{
  const int q0 = blockIdx.x << 5;
  const int h = blockIdx.y, b = blockIdx.z;
  const int t = threadIdx.x;
  const int lane = t & 63, wv = t >> 6;
  const int c = lane & 15, kg = lane >> 4;
  __shared__ f16 Qs[32][36];
  __shared__ f16 Ks[64][36];
  __shared__ f16 Vt[32][68];
  __shared__ f16 Pl[2][16][68];
  {
    const int row = t >> 2, part = t & 3;
    const float* src = qkv + ((size_t)(b * 896 + q0 + row) * 768) + h * 32 + part * 8;
    f16 tmp[8];
    #pragma unroll
    for (int j = 0; j < 8; ++j) tmp[j] = (f16)(src[j] * 0.17677669529663687f);
    *(f16x8*)&Qs[row][part * 8] = *(const f16x8*)tmp;
  }
  const f32x4 z4 = {0.f, 0.f, 0.f, 0.f};
  f32x4 o0 = z4, o1 = z4;
  float m[4] = {-1e30f, -1e30f, -1e30f, -1e30f};
  float l[4] = {0.f, 0.f, 0.f, 0.f};

  for (int k0 = 0; k0 < 896; k0 += 64) {
    __syncthreads();
    for (int i = t; i < 256; i += 128) {
      const int row = i >> 2, part = i & 3;
      const float* src = qkv + ((size_t)(b * 896 + k0 + row) * 768) + 256 + h * 32 + part * 8;
      f16 tmp[8];
      #pragma unroll
      for (int j = 0; j < 8; ++j) tmp[j] = (f16)src[j];
      *(f16x8*)&Ks[row][part * 8] = *(const f16x8*)tmp;
    }
    for (int i = t; i < 256; i += 128) {
      const int row = i >> 2, part = i & 3;
      const float* src = qkv + ((size_t)(b * 896 + k0 + row) * 768) + 512 + h * 32 + part * 8;
      #pragma unroll
      for (int j = 0; j < 8; ++j) Vt[part * 8 + j][row] = (f16)src[j];
    }
    __syncthreads();
    const f16x8 aq = *(const f16x8*)&Qs[wv * 16 + c][kg * 8];
    f32x4 s[4];
    #pragma unroll
    for (int fn = 0; fn < 4; ++fn)
      s[fn] = __builtin_amdgcn_mfma_f32_16x16x32_f16(
          aq, *(const f16x8*)&Ks[fn * 16 + c][kg * 8], z4, 0, 0, 0);
    float sc[4];
    #pragma unroll
    for (int r = 0; r < 4; ++r) {
      float v = fmaxf(fmaxf(s[0][r], s[1][r]), fmaxf(s[2][r], s[3][r]));
      #pragma unroll
      for (int msk = 1; msk < 16; msk <<= 1) v = fmaxf(v, __shfl_xor(v, msk));
      const float mn = fmaxf(m[r], v);
      sc[r] = __expf(m[r] - mn);
      m[r] = mn;
    }
    #pragma unroll
    for (int r = 0; r < 4; ++r) {
      float ps = 0.f;
      #pragma unroll
      for (int fn = 0; fn < 4; ++fn) {
        const float p = __expf(s[fn][r] - m[r]);
        ps += p;
        Pl[wv][kg * 4 + r][fn * 16 + c] = (f16)p;
      }
      #pragma unroll
      for (int msk = 1; msk < 16; msk <<= 1) ps += __shfl_xor(ps, msk);
      l[r] = l[r] * sc[r] + ps;
    }
    #pragma unroll
    for (int r = 0; r < 4; ++r) { o0[r] *= sc[r]; o1[r] *= sc[r]; }
    const f16x8 a0 = *(const f16x8*)&Pl[wv][c][kg * 8];
    const f16x8 a1 = *(const f16x8*)&Pl[wv][c][32 + kg * 8];
    o0 = __builtin_amdgcn_mfma_f32_16x16x32_f16(a0, *(const f16x8*)&Vt[c][kg * 8], o0, 0, 0, 0);
    o0 = __builtin_amdgcn_mfma_f32_16x16x32_f16(a1, *(const f16x8*)&Vt[c][32 + kg * 8], o0, 0, 0, 0);
    o1 = __builtin_amdgcn_mfma_f32_16x16x32_f16(a0, *(const f16x8*)&Vt[16 + c][kg * 8], o1, 0, 0, 0);
    o1 = __builtin_amdgcn_mfma_f32_16x16x32_f16(a1, *(const f16x8*)&Vt[16 + c][32 + kg * 8], o1, 0, 0, 0);
  }
  #pragma unroll
  for (int r = 0; r < 4; ++r) {
    const int row = q0 + wv * 16 + kg * 4 + r;
    const float inv = 1.0f / l[r];
    out[((size_t)(b * 896 + row) * 256) + h * 32 + c] = o0[r] * inv;
    out[((size_t)(b * 896 + row) * 256) + h * 32 + 16 + c] = o1[r] * inv;
  }
}

// ---------------------------------------------------------------- build inv table
__global__ __launch_bounds__(1024) void inv_k(const int* __restrict__ pc, int* __restrict__ inv)
{
  const int t = threadIdx.x;
  if (t < 1024) inv[t] = 0;
  __syncthreads();
  if (t < 640) {
    const int wide = (pc[3] == 0);
    int s = wide ? pc[4 * t] : pc[2 * t];
    int coord = wide ? pc[4 * t + 2] : pc[2 * t + 1];
    s &= 1;
    const int gs = 16 << s;
    const int k = 1 << (1 - s);
    const int r = (coord / gs) * k, c = (coord % gs) * k;
    for (int oi = 0; oi < k; ++oi)
      for (int oj = 0; oj < k; ++oj) {
        const int rr = r + oi, cc = c + oj;
        if (rr >= 0 && rr < 32 && cc >= 0 && cc < 32)
          inv[rr * 32 + cc] = t;
      }
  }
}

// ---------------------------------------------------------------- gather masks -> NHWC f16 img
__global__ __launch_bounds__(256) void gather16_k(
    const float* __restrict__ masks, const int* __restrict__ inv, f16* __restrict__ img)
{
  const int p = blockIdx.x & 1023, b = blockIdx.x >> 10, t = threadIdx.x;
  img[((size_t)blockIdx.x << 8) + t] = (f16)masks[((size_t)b * 640 + inv[p]) * 256 + t];
}

// ---------------------------------------------------------------- fused normalize+leaky helper
__device__ __forceinline__ f16x8 nrm8(f16x8 v, const float2* __restrict__ mrb, int cbase)
{
  #pragma unroll
  for (int j = 0; j < 8; ++j) {
    const float2 mv = mrb[cbase + j];
    float z = ((float)v[j] - mv.x) * mv.y;
    v[j] = (f16)(z >= 0.f ? z : 0.01f * z);
  }
  return v;
}

// ---------------------------------------------------------------- MFMA conv3x3 (64-co, bt9 staged)
// optional fused input norm; fused per-channel stats epilogue -> partial[b][tile][256]
template<bool NORM>
__global__ __launch_bounds__(256) void conv3m_k(
    const f16* __restrict__ x, const f16* __restrict__ wf, const float* __restrict__ bias,
    f16* __restrict__ y, int H, int W, const float2* __restrict__ mr, float2* __restrict__ partial)
{
  const int tilesx = W >> 4;
  const int ty0 = (blockIdx.x / tilesx) << 4, tx0 = (blockIdx.x % tilesx) << 4;
  const int co0 = blockIdx.y << 6;
  const int bb = blockIdx.z;
  const int t = threadIdx.x;
  const int lane = t & 63, wv = t >> 6;
  const int frow = lane & 15, kg = lane >> 4;
  const float2* mrb = NORM ? mr + bb * 256 : nullptr;
  __shared__ f16 halo[18][18][40];
  __shared__ f16 bt9[9][64][40];
  __shared__ float2 sred[4][64];
  f32x4 acc[4][4];
  #pragma unroll
  for (int i = 0; i < 4; ++i)
    #pragma unroll
    for (int j = 0; j < 4; ++j) acc[i][j] = (f32x4){0.f, 0.f, 0.f, 0.f};

  for (int c0 = 0; c0 < 256; c0 += 32) {
    __syncthreads();
    for (int i = t; i < 1296; i += 256) {
      const int cell = i >> 2, part = i & 3;
      const int hy = cell / 18, hx = cell - hy * 18;
      const int gy = ty0 + hy - 1, gx = tx0 + hx - 1;
      f16x8 v = {(f16)0,(f16)0,(f16)0,(f16)0,(f16)0,(f16)0,(f16)0,(f16)0};
      if (gy >= 0 && gy < H && gx >= 0 && gx < W) {
        v = *(const f16x8*)&x[(((size_t)bb * H + gy) * W + gx) * 256 + c0 + part * 8];
        if (NORM) v = nrm8(v, mrb, c0 + part * 8);
      }
      *(f16x8*)&halo[hy][hx][part * 8] = v;
    }
    for (int i = t; i < 2304; i += 256) {
      const int tap = i >> 8, rem = i & 255, co = rem >> 2, part = rem & 3;
      *(f16x8*)&bt9[tap][co][part * 8] =
          *(const f16x8*)&wf[(((size_t)tap * 256) + co0 + co) * 256 + c0 + part * 8];
    }
    __syncthreads();
    #pragma unroll
    for (int kyr = 0; kyr < 3; ++kyr)
      #pragma unroll
      for (int kx = 0; kx < 3; ++kx) {
        f16x8 af[4], bf[4];
        #pragma unroll
        for (int fm = 0; fm < 4; ++fm) {
          const int pos = wv * 64 + fm * 16 + frow;
          af[fm] = *(const f16x8*)&halo[(pos >> 4) + kyr][(pos & 15) + kx][kg * 8];
        }
        #pragma unroll
        for (int fn = 0; fn < 4; ++fn)
          bf[fn] = *(const f16x8*)&bt9[kyr * 3 + kx][fn * 16 + frow][kg * 8];
        #pragma unroll
        for (int fm = 0; fm < 4; ++fm)
          #pragma unroll
          for (int fn = 0; fn < 4; ++fn)
            acc[fm][fn] = __builtin_amdgcn_mfma_f32_16x16x32_f16(af[fm], bf[fn], acc[fm][fn], 0, 0, 0);
      }
  }
  float ps[4] = {0.f, 0.f, 0.f, 0.f}, ss[4] = {0.f, 0.f, 0.f, 0.f};
  #pragma unroll
  for (int fn = 0; fn < 4; ++fn) {
    const int col = co0 + fn * 16 + frow;
    const float bv = bias[col];
    #pragma unroll
    for (int fm = 0; fm < 4; ++fm)
      #pragma unroll
      for (int r = 0; r < 4; ++r) {
        const int pos = wv * 64 + fm * 16 + kg * 4 + r;
        const float v = acc[fm][fn][r] + bv;
        ps[fn] += v; ss[fn] += v * v;
        y[(((size_t)bb * H + ty0 + (pos >> 4)) * W + tx0 + (pos & 15)) * 256 + col] = (f16)v;
      }
  }
  #pragma unroll
  for (int fn = 0; fn < 4; ++fn)
    #pragma unroll
    for (int msk = 16; msk < 64; msk <<= 1) {
      ps[fn] += __shfl_xor(ps[fn], msk);
      ss[fn] += __shfl_xor(ss[fn], msk);
    }
  __syncthreads();
  if (kg == 0) {
    #pragma unroll
    for (int fn = 0; fn < 4; ++fn) sred[wv][fn * 16 + frow] = make_float2(ps[fn], ss[fn]);
  }
  __syncthreads();
  if (t < 64) {
    float a1 = 0.f, a2 = 0.f;
    #pragma unroll
    for (int w = 0; w < 4; ++w) { a1 += sred[w][t].x; a2 += sred[w][t].y; }
    partial[((size_t)bb * 256 + blockIdx.x) * 256 + co0 + t] = make_float2(a1, a2);
  }
}

// ---------------------------------------------------------------- MFMA convT 2x2 s2 (staged weights)
// fused input norm (always) + stats epilogue -> partial[b][tile*4+par][256]
__global__ __launch_bounds__(256) void convtm_k(
    const f16* __restrict__ x, const f16* __restrict__ wtp, const float* __restrict__ bias,
    f16* __restrict__ y, int H, int W, const float2* __restrict__ mr, float2* __restrict__ partial)
{
  const int tilesx = W >> 4;
  const int ty0 = (blockIdx.x / tilesx) << 4, tx0 = (blockIdx.x % tilesx) << 4;
  const int co0 = (blockIdx.y >> 2) << 6;
  const int par = blockIdx.y & 3;
  const int pa = par >> 1, pb = par & 1;
  const int bb = blockIdx.z;
  const int t = threadIdx.x;
  const int lane = t & 63, wv = t >> 6;
  const int frow = lane & 15, kg = lane >> 4;
  const float2* mrb = mr + bb * 256;
  __shared__ f16 at[256][40];
  __shared__ f16 btw[64][40];
  __shared__ float2 sred[4][64];
  f32x4 acc[4][4];
  #pragma unroll
  for (int i = 0; i < 4; ++i)
    #pragma unroll
    for (int j = 0; j < 4; ++j) acc[i][j] = (f32x4){0.f, 0.f, 0.f, 0.f};

  for (int c0 = 0; c0 < 256; c0 += 32) {
    __syncthreads();
    for (int i = t; i < 1024; i += 256) {
      const int cell = i >> 2, part = i & 3;
      const int gy = ty0 + (cell >> 4), gx = tx0 + (cell & 15);
      f16x8 v = *(const f16x8*)&x[(((size_t)bb * H + gy) * W + gx) * 256 + c0 + part * 8];
      *(f16x8*)&at[cell][part * 8] = nrm8(v, mrb, c0 + part * 8);
    }
    {
      const int i = t;
      const int co = i >> 2, part = i & 3;
      *(f16x8*)&btw[co][part * 8] =
          *(const f16x8*)&wtp[((size_t)par * 256 + co0 + co) * 256 + c0 + part * 8];
    }
    __syncthreads();
    f16x8 af[4], bf[4];
    #pragma unroll
    for (int fm = 0; fm < 4; ++fm)
      af[fm] = *(const f16x8*)&at[wv * 64 + fm * 16 + frow][kg * 8];
    #pragma unroll
    for (int fn = 0; fn < 4; ++fn)
      bf[fn] = *(const f16x8*)&btw[fn * 16 + frow][kg * 8];
    #pragma unroll
    for (int fm = 0; fm < 4; ++fm)
      #pragma unroll
      for (int fn = 0; fn < 4; ++fn)
        acc[fm][fn] = __builtin_amdgcn_mfma_f32_16x16x32_f16(af[fm], bf[fn], acc[fm][fn], 0, 0, 0);
  }
  const int HO = H << 1, WO = W << 1;
  float ps[4] = {0.f, 0.f, 0.f, 0.f}, ss[4] = {0.f, 0.f, 0.f, 0.f};
  #pragma unroll
  for (int fn = 0; fn < 4; ++fn) {
    const int col = co0 + fn * 16 + frow;
    const float bv = bias[col];
    #pragma unroll
    for (int fm = 0; fm < 4; ++fm)
      #pragma unroll
      for (int r = 0; r < 4; ++r) {
        const int pos = wv * 64 + fm * 16 + kg * 4 + r;
        const int oy = ((ty0 + (pos >> 4)) << 1) + pa;
        const int ox = ((tx0 + (pos & 15)) << 1) + pb;
        const float v = acc[fm][fn][r] + bv;
        ps[fn] += v; ss[fn] += v * v;
        y[(((size_t)bb * HO + oy) * WO + ox) * 256 + col] = (f16)v;
      }
  }
  #pragma unroll
  for (int fn = 0; fn < 4; ++fn)
    #pragma unroll
    for (int msk = 16; msk < 64; msk <<= 1) {
      ps[fn] += __shfl_xor(ps[fn], msk);
      ss[fn] += __shfl_xor(ss[fn], msk);
    }
  __syncthreads();
  if (kg == 0) {
    #pragma unroll
    for (int fn = 0; fn < 4; ++fn) sred[wv][fn * 16 + frow] = make_float2(ps[fn], ss[fn]);
  }
  __syncthreads();
  if (t < 64) {
    float a1 = 0.f, a2 = 0.f;
    #pragma unroll
    for (int w = 0; w < 4; ++w) { a1 += sred[w][t].x; a2 += sred[w][t].y; }
    partial[((size_t)bb * 256 + blockIdx.x * 4 + par) * 256 + co0 + t] = make_float2(a1, a2);
  }
}

// ---------------------------------------------------------------- stats2 (runtime NS, parallel)
__global__ __launch_bounds__(256) void stats2v2_k(
    const float2* __restrict__ partial, float2* __restrict__ mr, int HW, int NS)
{
  const int cg = blockIdx.x, b = blockIdx.y, t = threadIdx.x;
  const int chl = t & 31, g = t >> 5;
  const int ch = cg * 32 + chl;
  float s1 = 0.f, s2 = 0.f;
  for (int s = g; s < NS; s += 8) {
    const float2 v = partial[((size_t)b * 256 + s) * 256 + ch];
    s1 += v.x; s2 += v.y;
  }
  __shared__ float r1[8][32], r2[8][32];
  r1[g][chl] = s1; r2[g][chl] = s2;
  __syncthreads();
  if (t < 32) {
    float a1 = 0.f, a2 = 0.f;
    #pragma unroll
    for (int gg = 0; gg < 8; ++gg) { a1 += r1[gg][t]; a2 += r2[gg][t]; }
    const float m = a1 / (float)HW;
    const float var = fmaxf(a2 / (float)HW - m * m, 0.f);
    mr[b * 256 + cg * 32 + t] = make_float2(m, rsqrtf(var + 1e-5f));
  }
}

// ---------------------------------------------------------------- MFMA out conv 3x3; weights direct; fused input norm
__global__ __launch_bounds__(256) void convoutm2_k(
    const f16* __restrict__ x, const f16* __restrict__ wocp, const float* __restrict__ bias,
    void* __restrict__ yv, const int* __restrict__ flags, const float2* __restrict__ mr)
{
  const int ty0 = (blockIdx.x >> 4) << 4, tx0 = (blockIdx.x & 15) << 4;
  const int b = blockIdx.y;
  const int t = threadIdx.x;
  const int lane = t & 63, wv = t >> 6;
  const int frow = lane & 15, kg = lane >> 4;
  const float2* mrb = mr + b * 256;
  __shared__ f16 halo[18][18][40];
  f32x4 acc[4];
  #pragma unroll
  for (int i = 0; i < 4; ++i) acc[i] = (f32x4){0.f, 0.f, 0.f, 0.f};

  for (int c0 = 0; c0 < 256; c0 += 32) {
    __syncthreads();
    for (int i = t; i < 1296; i += 256) {
      const int cell = i >> 2, part = i & 3;
      const int hy = cell / 18, hx = cell - hy * 18;
      const int gy = ty0 + hy - 1, gx = tx0 + hx - 1;
      f16x8 v = {(f16)0,(f16)0,(f16)0,(f16)0,(f16)0,(f16)0,(f16)0,(f16)0};
      if ((unsigned)gy < 256u && (unsigned)gx < 256u) {
        v = *(const f16x8*)&x[(((size_t)b * 256 + gy) * 256 + gx) * 256 + c0 + part * 8];
        v = nrm8(v, mrb, c0 + part * 8);
      }
      *(f16x8*)&halo[hy][hx][part * 8] = v;
    }
    __syncthreads();
    #pragma unroll
    for (int kyr = 0; kyr < 3; ++kyr)
      #pragma unroll
      for (int kx = 0; kx < 3; ++kx) {
        const int tap = kyr * 3 + kx;
        const f16x8 bf = *(const f16x8*)&wocp[((size_t)(tap * 16 + frow)) * 256 + c0 + kg * 8];
        #pragma unroll
        for (int fm = 0; fm < 4; ++fm) {
          const int pos = wv * 64 + fm * 16 + frow;
          const f16x8 af = *(const f16x8*)&halo[(pos >> 4) + kyr][(pos & 15) + kx][kg * 8];
          acc[fm] = __builtin_amdgcn_mfma_f32_16x16x32_f16(af, bf, acc[fm], 0, 0, 0);
        }
      }
  }
  if (frow < 3) {
    const int fp32 = flags[0];
    const float bv = bias[frow];
    #pragma unroll
    for (int fm = 0; fm < 4; ++fm)
      #pragma unroll
      for (int r = 0; r < 4; ++r) {
        const int pos = wv * 64 + fm * 16 + kg * 4 + r;
        const int oy = ty0 + (pos >> 4), ox = tx0 + (pos & 15);
        const size_t oidx = (((size_t)b * 3 + frow) * 256 + oy) * 256 + ox;
        const float v = acc[fm][r] + bv;
        if (fp32) ((float*)yv)[oidx] = v;
        else      ((bf16*)yv)[oidx] = __float2bfloat16(v);
      }
  }
}

// ================================================================ host
extern "C" void kernel_launch(void* const* d_in, const int* in_sizes, int n_in,
                              void* d_out, int out_size, void* d_ws, size_t ws_size,
                              hipStream_t stream) {
  (void)in_sizes; (void)n_in; (void)out_size; (void)ws_size;
  const int* pc = (const int*)d_in[1];

  float* P = (float*)d_ws;
  size_t off = 0;
  CvtDesc cd{};
  int seg = 0;
  auto alloc = [&](size_t n) { float* p = P + off; off += n; return p; };
  auto allocCv = [&](int idx, size_t n) {
    float* p = P + off;
    cd.src[seg] = d_in[idx]; cd.dstOff[seg] = (unsigned)off; cd.n[seg] = (unsigned)n;
    ++seg; off += n; return p;
  };

  // ---- persistent small region ----
  int*    flags   = (int*)alloc(16);
  int*    invbuf  = (int*)alloc(1024);
  float2* partial = (float2*)alloc(262144);     // 2 x 256 slots x 256 ch float2
  float2* mr1     = (float2*)alloc(1024);
  float* pdb   = allocCv(3, 256);
  float* pw1   = allocCv(4, 512);
  float* pb1   = allocCv(5, 256);
  float* pb2   = allocCv(7, 256);
  float* pln1g = allocCv(9, 512);
  float* pln1b = allocCv(10, 512);
  float* pqkvb = allocCv(12, 1536);
  float* pattb = allocCv(14, 512);
  float* pln2g = allocCv(15, 512);
  float* pln2b = allocCv(16, 512);
  float* pm1b  = allocCv(18, 2048);
  float* pm2b  = allocCv(20, 512);
  float* pdecg = allocCv(21, 256);
  float* pdecb = allocCv(22, 256);
  float* pmg   = allocCv(25, 256);
  float* pmb   = allocCv(26, 256);
  float* pucb  = allocCv(28, 768);
  float* putb  = allocCv(30, 768);
  float* pocw  = allocCv(31, 6912);
  float* pocb  = allocCv(32, 16);
  off = (off + 255) & ~(size_t)255;
  f16* wf3  = (f16*)alloc(884736);
  f16* wt   = (f16*)alloc(393216);
  f16* wocp = (f16*)alloc(18432);
  off = (off + 255) & ~(size_t)255;

  // ---- zone A: big fp32 params + transformer scratch, later overlaid by R2 (f16) ----
  float* zoneA = P + off;
  f16*   R2h   = (f16*)zoneA;
  {
    size_t zo = off;
    auto zCv = [&](int idx, size_t n) {
      float* p = P + zo;
      cd.src[seg] = d_in[idx]; cd.dstOff[seg] = (unsigned)zo; cd.n[seg] = (unsigned)n;
      ++seg; zo += n; return p;
    };
    float* px    = zCv(0, 655360);
    float* pdw   = zCv(2, 131072);
    float* pw2   = zCv(6, 65536);
    float* pcls  = zCv(8, 65536);
    float* pqkvw = zCv(11, 393216);
    float* pattw = zCv(13, 131072);
    float* pm1w  = zCv(17, 524288);
    float* pm2w  = zCv(19, 524288);
    float* pprp  = zCv(23, 65536);
    float* pprc  = zCv(24, 65536);
    float* pucw  = zCv(27, 1769472);
    float* putw  = zCv(29, 786432);
    float* xbuf   = P + zo; zo += 458752;
    float* hbuf   = P + zo; zo += 458752;
    float* qkvbuf = P + zo; zo += 1376256;
    float* hidbuf = P + zo; zo += 1835008;
    float* posbuf = P + zo; zo += 163840;
    float* patbuf = P + zo; zo += 327680;
    float* clsbuf = P + zo; zo += 131072;
    float* masksb = P + zo; zo += 327680;
    off += 16777216;
    f16* R0h = (f16*)(P + off); off += 4194304;
    f16* R1h = (f16*)(P + off); off += 4194304;

    // 0) detect dtype, convert inputs to fp32, prep conv weights
    detect_k<<<1, 64, 0, stream>>>((const unsigned short*)d_in[0], flags);
    cvtall_k<<<dim3(256, NSEG), 256, 0, stream>>>(cd, P, flags);
    prepw_k<<<2048, 256, 0, stream>>>(pucw, putw, pocw, wf3, wt, wocp);

    // 1) positional MLP + projection + assembly
    posh_k<<<640, 256, 0, stream>>>(pc, pw1, pb1, patbuf);
    gemm64_k<false, 0><<<dim3(4, 10), 256, 0, stream>>>(
        patbuf, pw2, pb2, nullptr, posbuf, 640, 256, 256);
    gemm64_k<false, 0><<<dim3(4, 20), 256, 0, stream>>>(
        px, pdw, pdb, nullptr, hidbuf, 1280, 256, 512);
    assemble_k<<<1792, 256, 0, stream>>>(hidbuf, posbuf, pcls, xbuf);

    // 2) transformer blocks
    for (int l = 0; l < 2; ++l) {
      ln_k<<<1792, 256, 0, stream>>>(xbuf, hbuf, pln1g + l * 256, pln1b + l * 256);
      gemm64_k<false, 0><<<dim3(12, 28), 256, 0, stream>>>(
          hbuf, pqkvw + (size_t)l * 196608, pqkvb + l * 768, nullptr, qkvbuf, 1792, 768, 256);
      attnm_k<<<dim3(28, 8, 2), 128, 0, stream>>>(qkvbuf, hbuf);
      gemm64_k<false, 0><<<dim3(4, 28), 256, 0, stream>>>(
          hbuf, pattw + (size_t)l * 65536, pattb + l * 256, xbuf, xbuf, 1792, 256, 256);
      ln_k<<<1792, 256, 0, stream>>>(xbuf, hbuf, pln2g + l * 256, pln2b + l * 256);
      gemm64_k<false, 1><<<dim3(16, 28), 256, 0, stream>>>(
          hbuf, pm1w + (size_t)l * 262144, pm1b + l * 1024, nullptr, hidbuf, 1792, 1024, 256);
      gemm64_k<false, 0><<<dim3(4, 28), 256, 0, stream>>>(
          hidbuf, pm2w + (size_t)l * 262144, pm2b + l * 256, xbuf, xbuf, 1792, 256, 1024);
    }

    // 3) decoder head
    ln_k<<<1792, 256, 0, stream>>>(xbuf, hbuf, pdecg, pdecb);
    for (int b = 0; b < 2; ++b) {
      gemm64_k<false, 0><<<dim3(4, 10), 256, 0, stream>>>(
          hbuf + (size_t)b * 896 * 256, pprp, nullptr, nullptr,
          patbuf + (size_t)b * 640 * 256, 640, 256, 256);
      gemm64_k<false, 0><<<dim3(4, 4), 256, 0, stream>>>(
          hbuf + ((size_t)b * 896 + 640) * 256, pprc, nullptr, nullptr,
          clsbuf + (size_t)b * 65536, 256, 256, 256);
    }
    l2n_k<<<1280, 256, 0, stream>>>(patbuf);
    l2n_k<<<512, 256, 0, stream>>>(clsbuf);
    for (int b = 0; b < 2; ++b) {
      gemm64_k<true, 0><<<dim3(4, 10), 256, 0, stream>>>(
          patbuf + (size_t)b * 163840, clsbuf + (size_t)b * 65536, nullptr, nullptr,
          masksb + (size_t)b * 163840, 640, 256, 256);
    }
    ln_k<<<1280, 256, 0, stream>>>(masksb, masksb, pmg, pmb);

    // 4) scatter table + gather
    inv_k<<<1, 1024, 0, stream>>>(pc, invbuf);
    gather16_k<<<2048, 256, 0, stream>>>(masksb, invbuf, R0h);

    // 5) MFMA conv decoder with fused stats+norm
    int H = 32;
    for (int i = 0; i < 3; ++i) {
      const int tiles = (H / 16) * (H / 16);
      if (i == 0)
        conv3m_k<false><<<dim3(tiles, 4, 2), 256, 0, stream>>>(
            R0h, wf3, pucb, R1h, H, H, nullptr, partial);
      else
        conv3m_k<true><<<dim3(tiles, 4, 2), 256, 0, stream>>>(
            R0h, wf3 + (size_t)i * 9 * 65536, pucb + i * 256, R1h, H, H, mr1, partial);
      stats2v2_k<<<dim3(8, 2), 256, 0, stream>>>(partial, mr1, H * H, tiles);
      f16* dst = (i == 2) ? R2h : R0h;
      convtm_k<<<dim3(tiles, 16, 2), 256, 0, stream>>>(
          R1h, wt + (size_t)i * 4 * 65536, putb + i * 256, dst, H, H, mr1, partial);
      stats2v2_k<<<dim3(8, 2), 256, 0, stream>>>(partial, mr1, 4 * H * H, tiles * 4);
      H *= 2;
    }

    // 6) output conv 256 -> 3 via MFMA (fused input norm)
    convoutm2_k<<<dim3(256, 2), 256, 0, stream>>>(R2h, wocp, pocb, d_out, flags, mr1);
  }
}

// Round 17
// 643.447 us; speedup vs baseline: 1.0739x; 1.0739x over previous
//
#include <hip/hip_runtime.h>
#include <hip/hip_bf16.h>

typedef __hip_bfloat16 bf16;
typedef _Float16 f16;
typedef __attribute__((ext_vector_type(8))) _Float16 f16x8;
typedef __attribute__((ext_vector_type(4))) float f32x4;

// ---------------------------------------------------------------- dtype detector (wave-parallel)
__global__ void detect_k(const unsigned short* __restrict__ xh, int* __restrict__ flags)
{
  const int t = threadIdx.x;   // 64
  int w = 0;
  for (int i = t; i < 512; i += 64) {
    const int e = (xh[i] >> 7) & 0xFF;
    if (e == 0xFF || e >= 0x88) ++w;
  }
  #pragma unroll
  for (int msk = 1; msk < 64; msk <<= 1) w += __shfl_xor(w, msk);
  if (t == 0) flags[0] = (w > 32) ? 1 : 0;
}

// ---------------------------------------------------------------- batched input->fp32 convert
#define NSEG 33
struct CvtDesc {
  const void* src[NSEG];
  unsigned dstOff[NSEG];
  unsigned n[NSEG];
};
__global__ __launch_bounds__(256) void cvtall_k(
    CvtDesc d, float* __restrict__ P, const int* __restrict__ flags)
{
  const int s = blockIdx.y;
  const unsigned n = d.n[s];
  const int fp32 = flags[0];
  float* dst = P + d.dstOff[s];
  const unsigned stride = gridDim.x * 256u;
  if (fp32) {
    const float* src = (const float*)d.src[s];
    for (unsigned i = blockIdx.x * 256u + threadIdx.x; i < n; i += stride) dst[i] = src[i];
  } else {
    const bf16* src = (const bf16*)d.src[s];
    for (unsigned i = blockIdx.x * 256u + threadIdx.x; i < n; i += stride)
      dst[i] = __bfloat162float(src[i]);
  }
}

// ---------------------------------------------------------------- conv weight prep
__global__ __launch_bounds__(256) void prepw_k(
    const float* __restrict__ ucw, const float* __restrict__ utw, const float* __restrict__ ocw,
    f16* __restrict__ wf3, f16* __restrict__ wt, f16* __restrict__ wocp)
{
  const int n1 = 3 * 9 * 65536;
  const int n2 = 3 * 4 * 65536;
  const int n3 = 9 * 16 * 256;
  for (int i = blockIdx.x * 256 + threadIdx.x; i < n1 + n2 + n3; i += gridDim.x * 256) {
    if (i < n1) {
      const int st = i / 589824, r = i % 589824;
      const int kk = r / 65536, rr = r % 65536;
      const int co = rr >> 8, ci = rr & 255;
      wf3[i] = (f16)ucw[(((size_t)st * 256 + co) * 256 + ci) * 9 + kk];
    } else if (i < n1 + n2) {
      const int j = i - n1;
      const int st = j / 262144, r = j % 262144;
      const int ij = r / 65536, rr = r % 65536;
      const int co = rr >> 8, ci = rr & 255;
      wt[j] = (f16)utw[(((size_t)st * 256 + ci) * 256 + co) * 4 + ij];
    } else {
      const int j = i - n1 - n2;
      const int tap = j >> 12, rem = j & 4095;
      const int co = rem >> 8, ci = rem & 255;
      wocp[j] = (co < 3) ? (f16)ocw[(((size_t)co * 256) + ci) * 9 + tap] : (f16)0.f;
    }
  }
}

// ---------------------------------------------------------------- MFMA GEMM 64x64 tile, 4 waves
template<bool TRB, int ACT>
__global__ __launch_bounds__(256) void gemm64_k(
    const float* __restrict__ A, const float* __restrict__ B,
    const float* __restrict__ bias, const float* __restrict__ res,
    float* __restrict__ C, int M, int N, int K)
{
  const int m0 = blockIdx.y << 6, n0 = blockIdx.x << 6;
  const int t = threadIdx.x;
  const int lane = t & 63, wv = t >> 6;
  const int wm = wv >> 1, wn = wv & 1;
  const int frow = lane & 15, kg = lane >> 4;
  __shared__ f16 As[64][40];
  __shared__ f16 Bs[64][40];
  f32x4 acc[2][2];
  #pragma unroll
  for (int i = 0; i < 2; ++i)
    #pragma unroll
    for (int j = 0; j < 2; ++j) acc[i][j] = (f32x4){0.f, 0.f, 0.f, 0.f};

  for (int k0 = 0; k0 < K; k0 += 32) {
    __syncthreads();
    {
      const int row = t >> 2, kh = (t & 3) << 3;
      const float* ap = A + (size_t)(m0 + row) * K + k0 + kh;
      #pragma unroll
      for (int j = 0; j < 8; ++j) As[row][kh + j] = (f16)ap[j];
    }
    if (TRB) {
      const int row = t >> 2, kh = (t & 3) << 3;
      const float* bp = B + (size_t)(n0 + row) * K + k0 + kh;
      #pragma unroll
      for (int j = 0; j < 8; ++j) Bs[row][kh + j] = (f16)bp[j];
    } else {
      #pragma unroll
      for (int i2 = 0; i2 < 8; ++i2) {
        const int i = i2 * 256 + t;
        const int n = i & 63, kk = i >> 6;
        Bs[n][kk] = (f16)B[(size_t)(k0 + kk) * N + n0 + n];
      }
    }
    __syncthreads();
    f16x8 af[2], bf[2];
    #pragma unroll
    for (int fm = 0; fm < 2; ++fm)
      af[fm] = *(const f16x8*)&As[wm * 32 + fm * 16 + frow][kg * 8];
    #pragma unroll
    for (int fn = 0; fn < 2; ++fn)
      bf[fn] = *(const f16x8*)&Bs[wn * 32 + fn * 16 + frow][kg * 8];
    #pragma unroll
    for (int fm = 0; fm < 2; ++fm)
      #pragma unroll
      for (int fn = 0; fn < 2; ++fn)
        acc[fm][fn] = __builtin_amdgcn_mfma_f32_16x16x32_f16(af[fm], bf[fn], acc[fm][fn], 0, 0, 0);
  }
  #pragma unroll
  for (int fn = 0; fn < 2; ++fn) {
    const int col = n0 + wn * 32 + fn * 16 + frow;
    const float bv = bias ? bias[col] : 0.f;
    #pragma unroll
    for (int fm = 0; fm < 2; ++fm)
      #pragma unroll
      for (int r = 0; r < 4; ++r) {
        const int row = m0 + wm * 32 + fm * 16 + kg * 4 + r;
        float v = acc[fm][fn][r] + bv;
        if (ACT == 1) v = 0.5f * v * (1.0f + erff(v * 0.70710678118654752f));
        if (res) v += res[(size_t)row * N + col];
        C[(size_t)row * N + col] = v;
      }
  }
}

// ---------------------------------------------------------------- LayerNorm (row len 256, shfl reduce)
__global__ __launch_bounds__(256) void ln_k(
    const float* __restrict__ in, float* __restrict__ out,
    const float* __restrict__ g, const float* __restrict__ b)
{
  const int row = blockIdx.x, t = threadIdx.x;
  __shared__ float ws1[4], ws2[4];
  const float x = in[(size_t)row * 256 + t];
  float v = x;
  #pragma unroll
  for (int msk = 1; msk < 64; msk <<= 1) v += __shfl_xor(v, msk);
  if ((t & 63) == 0) ws1[t >> 6] = v;
  __syncthreads();
  const float m = (ws1[0] + ws1[1] + ws1[2] + ws1[3]) * (1.0f / 256.0f);
  const float d = x - m;
  float v2 = d * d;
  #pragma unroll
  for (int msk = 1; msk < 64; msk <<= 1) v2 += __shfl_xor(v2, msk);
  if ((t & 63) == 0) ws2[t >> 6] = v2;
  __syncthreads();
  const float rstd = rsqrtf((ws2[0] + ws2[1] + ws2[2] + ws2[3]) * (1.0f / 256.0f) + 1e-5f);
  out[(size_t)row * 256 + t] = d * rstd * g[t] + b[t];
}

// ---------------------------------------------------------------- L2 normalize rows (shfl reduce)
__global__ __launch_bounds__(256) void l2n_k(float* __restrict__ x)
{
  const int row = blockIdx.x, t = threadIdx.x;
  __shared__ float ws[4];
  const float v = x[(size_t)row * 256 + t];
  float s = v * v;
  #pragma unroll
  for (int msk = 1; msk < 64; msk <<= 1) s += __shfl_xor(s, msk);
  if ((t & 63) == 0) ws[t >> 6] = s;
  __syncthreads();
  x[(size_t)row * 256 + t] = v * rsqrtf(ws[0] + ws[1] + ws[2] + ws[3]);
}

// ---------------------------------------------------------------- pos hidden (elementwise)
__global__ __launch_bounds__(256) void posh_k(
    const int* __restrict__ pc, const float* __restrict__ w1, const float* __restrict__ b1,
    float* __restrict__ hid)
{
  const int n = blockIdx.x, t = threadIdx.x;
  const int wide = (pc[3] == 0);
  const int sv = wide ? pc[4 * n] : pc[2 * n];
  const int cv = wide ? pc[4 * n + 2] : pc[2 * n + 1];
  const float hv = (float)sv * w1[t] + (float)cv * w1[256 + t] + b1[t];
  hid[(size_t)n * 256 + t] = hv > 0.0f ? hv : 0.0f;
}

// ---------------------------------------------------------------- assemble x = [proj+pos ; cls]
__global__ __launch_bounds__(256) void assemble_k(
    const float* __restrict__ proj, const float* __restrict__ pos,
    const float* __restrict__ cls, float* __restrict__ xb)
{
  const int row = blockIdx.x;
  const int b = row / 896, n = row % 896, t = threadIdx.x;
  float v;
  if (n < 640) v = proj[((size_t)b * 640 + n) * 256 + t] + pos[n * 256 + t];
  else         v = cls[(n - 640) * 256 + t];
  xb[(size_t)row * 256 + t] = v;
}

// ---------------------------------------------------------------- MFMA flash attention
__global__ __launch_bounds__(128) void attnm_k(
    const float* __restrict__ qkv, float* __restrict__ out)
{
  const int q0 = blockIdx.x << 5;
  const int h = blockIdx.y, b = blockIdx.z;
  const int t = threadIdx.x;
  const int lane = t & 63, wv = t >> 6;
  const int c = lane & 15, kg = lane >> 4;
  __shared__ f16 Qs[32][36];
  __shared__ f16 Ks[64][36];
  __shared__ f16 Vt[32][68];
  __shared__ f16 Pl[2][16][68];
  {
    const int row = t >> 2, part = t & 3;
    const float* src = qkv + ((size_t)(b * 896 + q0 + row) * 768) + h * 32 + part * 8;
    f16 tmp[8];
    #pragma unroll
    for (int j = 0; j < 8; ++j) tmp[j] = (f16)(src[j] * 0.17677669529663687f);
    *(f16x8*)&Qs[row][part * 8] = *(const f16x8*)tmp;
  }
  const f32x4 z4 = {0.f, 0.f, 0.f, 0.f};
  f32x4 o0 = z4, o1 = z4;
  float m[4] = {-1e30f, -1e30f, -1e30f, -1e30f};
  float l[4] = {0.f, 0.f, 0.f, 0.f};

  for (int k0 = 0; k0 < 896; k0 += 64) {
    __syncthreads();
    for (int i = t; i < 256; i += 128) {
      const int row = i >> 2, part = i & 3;
      const float* src = qkv + ((size_t)(b * 896 + k0 + row) * 768) + 256 + h * 32 + part * 8;
      f16 tmp[8];
      #pragma unroll
      for (int j = 0; j < 8; ++j) tmp[j] = (f16)src[j];
      *(f16x8*)&Ks[row][part * 8] = *(const f16x8*)tmp;
    }
    for (int i = t; i < 256; i += 128) {
      const int row = i >> 2, part = i & 3;
      const float* src = qkv + ((size_t)(b * 896 + k0 + row) * 768) + 512 + h * 32 + part * 8;
      #pragma unroll
      for (int j = 0; j < 8; ++j) Vt[part * 8 + j][row] = (f16)src[j];
    }
    __syncthreads();
    const f16x8 aq = *(const f16x8*)&Qs[wv * 16 + c][kg * 8];
    f32x4 s[4];
    #pragma unroll
    for (int fn = 0; fn < 4; ++fn)
      s[fn] = __builtin_amdgcn_mfma_f32_16x16x32_f16(
          aq, *(const f16x8*)&Ks[fn * 16 + c][kg * 8], z4, 0, 0, 0);
    float sc[4];
    #pragma unroll
    for (int r = 0; r < 4; ++r) {
      float v = fmaxf(fmaxf(s[0][r], s[1][r]), fmaxf(s[2][r], s[3][r]));
      #pragma unroll
      for (int msk = 1; msk < 16; msk <<= 1) v = fmaxf(v, __shfl_xor(v, msk));
      const float mn = fmaxf(m[r], v);
      sc[r] = __expf(m[r] - mn);
      m[r] = mn;
    }
    #pragma unroll
    for (int r = 0; r < 4; ++r) {
      float ps = 0.f;
      #pragma unroll
      for (int fn = 0; fn < 4; ++fn) {
        const float p = __expf(s[fn][r] - m[r]);
        ps += p;
        Pl[wv][kg * 4 + r][fn * 16 + c] = (f16)p;
      }
      #pragma unroll
      for (int msk = 1; msk < 16; msk <<= 1) ps += __shfl_xor(ps, msk);
      l[r] = l[r] * sc[r] + ps;
    }
    #pragma unroll
    for (int r = 0; r < 4; ++r) { o0[r] *= sc[r]; o1[r] *= sc[r]; }
    const f16x8 a0 = *(const f16x8*)&Pl[wv][c][kg * 8];
    const f16x8 a1 = *(const f16x8*)&Pl[wv][c][32 + kg * 8];
    o0 = __builtin_amdgcn_mfma_f32_16x16x32_f16(a0, *(const f16x8*)&Vt[c][kg * 8], o0, 0, 0, 0);
    o0 = __builtin_amdgcn_mfma_f32_16x16x32_f16(a1, *(const f16x8*)&Vt[c][32 + kg * 8], o0, 0, 0, 0);
    o1 = __builtin_amdgcn_mfma_f32_16x16x32_f16(a0, *(const f16x8*)&Vt[16 + c][kg * 8], o1, 0, 0, 0);
    o1 = __builtin_amdgcn_mfma_f32_16x16x32_f16(a1, *(const f16x8*)&Vt[16 + c][32 + kg * 8], o1, 0, 0, 0);
  }
  #pragma unroll
  for (int r = 0; r < 4; ++r) {
    const int row = q0 + wv * 16 + kg * 4 + r;
    const float inv = 1.0f / l[r];
    out[((size_t)(b * 896 + row) * 256) + h * 32 + c] = o0[r] * inv;
    out[((size_t)(b * 896 + row) * 256) + h * 32 + 16 + c] = o1[r] * inv;
  }
}

// ---------------------------------------------------------------- build inv table
__global__ __launch_bounds__(1024) void inv_k(const int* __restrict__ pc, int* __restrict__ inv)
{
  const int t = threadIdx.x;
  if (t < 1024) inv[t] = 0;
  __syncthreads();
  if (t < 640) {
    const int wide = (pc[3] == 0);
    int s = wide ? pc[4 * t] : pc[2 * t];
    int coord = wide ? pc[4 * t + 2] : pc[2 * t + 1];
    s &= 1;
    const int gs = 16 << s;
    const int k = 1 << (1 - s);
    const int r = (coord / gs) * k, c = (coord % gs) * k;
    for (int oi = 0; oi < k; ++oi)
      for (int oj = 0; oj < k; ++oj) {
        const int rr = r + oi, cc = c + oj;
        if (rr >= 0 && rr < 32 && cc >= 0 && cc < 32)
          inv[rr * 32 + cc] = t;
      }
  }
}

// ---------------------------------------------------------------- gather masks -> NHWC f16 img
__global__ __launch_bounds__(256) void gather16_k(
    const float* __restrict__ masks, const int* __restrict__ inv, f16* __restrict__ img)
{
  const int p = blockIdx.x & 1023, b = blockIdx.x >> 10, t = threadIdx.x;
  img[((size_t)blockIdx.x << 8) + t] = (f16)masks[((size_t)b * 640 + inv[p]) * 256 + t];
}

// ---------------------------------------------------------------- MFMA conv3x3 (64-co, bt9 staged)
// fused per-channel stats epilogue -> partial[b][tile][256]; input read as-is (pre-normalized)
__global__ __launch_bounds__(256) void conv3m_k(
    const f16* __restrict__ x, const f16* __restrict__ wf, const float* __restrict__ bias,
    f16* __restrict__ y, int H, int W, float2* __restrict__ partial)
{
  const int tilesx = W >> 4;
  const int ty0 = (blockIdx.x / tilesx) << 4, tx0 = (blockIdx.x % tilesx) << 4;
  const int co0 = blockIdx.y << 6;
  const int bb = blockIdx.z;
  const int t = threadIdx.x;
  const int lane = t & 63, wv = t >> 6;
  const int frow = lane & 15, kg = lane >> 4;
  __shared__ f16 halo[18][18][40];
  __shared__ f16 bt9[9][64][40];
  __shared__ float2 sred[4][64];
  f32x4 acc[4][4];
  #pragma unroll
  for (int i = 0; i < 4; ++i)
    #pragma unroll
    for (int j = 0; j < 4; ++j) acc[i][j] = (f32x4){0.f, 0.f, 0.f, 0.f};

  for (int c0 = 0; c0 < 256; c0 += 32) {
    __syncthreads();
    for (int i = t; i < 1296; i += 256) {
      const int cell = i >> 2, part = i & 3;
      const int hy = cell / 18, hx = cell - hy * 18;
      const int gy = ty0 + hy - 1, gx = tx0 + hx - 1;
      f16x8 v = {(f16)0,(f16)0,(f16)0,(f16)0,(f16)0,(f16)0,(f16)0,(f16)0};
      if (gy >= 0 && gy < H && gx >= 0 && gx < W)
        v = *(const f16x8*)&x[(((size_t)bb * H + gy) * W + gx) * 256 + c0 + part * 8];
      *(f16x8*)&halo[hy][hx][part * 8] = v;
    }
    for (int i = t; i < 2304; i += 256) {
      const int tap = i >> 8, rem = i & 255, co = rem >> 2, part = rem & 3;
      *(f16x8*)&bt9[tap][co][part * 8] =
          *(const f16x8*)&wf[(((size_t)tap * 256) + co0 + co) * 256 + c0 + part * 8];
    }
    __syncthreads();
    #pragma unroll
    for (int kyr = 0; kyr < 3; ++kyr)
      #pragma unroll
      for (int kx = 0; kx < 3; ++kx) {
        f16x8 af[4], bf[4];
        #pragma unroll
        for (int fm = 0; fm < 4; ++fm) {
          const int pos = wv * 64 + fm * 16 + frow;
          af[fm] = *(const f16x8*)&halo[(pos >> 4) + kyr][(pos & 15) + kx][kg * 8];
        }
        #pragma unroll
        for (int fn = 0; fn < 4; ++fn)
          bf[fn] = *(const f16x8*)&bt9[kyr * 3 + kx][fn * 16 + frow][kg * 8];
        #pragma unroll
        for (int fm = 0; fm < 4; ++fm)
          #pragma unroll
          for (int fn = 0; fn < 4; ++fn)
            acc[fm][fn] = __builtin_amdgcn_mfma_f32_16x16x32_f16(af[fm], bf[fn], acc[fm][fn], 0, 0, 0);
      }
  }
  float ps[4] = {0.f, 0.f, 0.f, 0.f}, ss[4] = {0.f, 0.f, 0.f, 0.f};
  #pragma unroll
  for (int fn = 0; fn < 4; ++fn) {
    const int col = co0 + fn * 16 + frow;
    const float bv = bias[col];
    #pragma unroll
    for (int fm = 0; fm < 4; ++fm)
      #pragma unroll
      for (int r = 0; r < 4; ++r) {
        const int pos = wv * 64 + fm * 16 + kg * 4 + r;
        const float v = acc[fm][fn][r] + bv;
        ps[fn] += v; ss[fn] += v * v;
        y[(((size_t)bb * H + ty0 + (pos >> 4)) * W + tx0 + (pos & 15)) * 256 + col] = (f16)v;
      }
  }
  #pragma unroll
  for (int fn = 0; fn < 4; ++fn)
    #pragma unroll
    for (int msk = 16; msk < 64; msk <<= 1) {
      ps[fn] += __shfl_xor(ps[fn], msk);
      ss[fn] += __shfl_xor(ss[fn], msk);
    }
  __syncthreads();
  if (kg == 0) {
    #pragma unroll
    for (int fn = 0; fn < 4; ++fn) sred[wv][fn * 16 + frow] = make_float2(ps[fn], ss[fn]);
  }
  __syncthreads();
  if (t < 64) {
    float a1 = 0.f, a2 = 0.f;
    #pragma unroll
    for (int w = 0; w < 4; ++w) { a1 += sred[w][t].x; a2 += sred[w][t].y; }
    partial[((size_t)bb * 256 + blockIdx.x) * 256 + co0 + t] = make_float2(a1, a2);
  }
}

// ---------------------------------------------------------------- MFMA convT 2x2 s2 (staged weights)
// fused stats epilogue -> partial[b][tile*4+par][256]; input read as-is (pre-normalized)
__global__ __launch_bounds__(256) void convtm_k(
    const f16* __restrict__ x, const f16* __restrict__ wtp, const float* __restrict__ bias,
    f16* __restrict__ y, int H, int W, float2* __restrict__ partial)
{
  const int tilesx = W >> 4;
  const int ty0 = (blockIdx.x / tilesx) << 4, tx0 = (blockIdx.x % tilesx) << 4;
  const int co0 = (blockIdx.y >> 2) << 6;
  const int par = blockIdx.y & 3;
  const int pa = par >> 1, pb = par & 1;
  const int bb = blockIdx.z;
  const int t = threadIdx.x;
  const int lane = t & 63, wv = t >> 6;
  const int frow = lane & 15, kg = lane >> 4;
  __shared__ f16 at[256][40];
  __shared__ f16 btw[64][40];
  __shared__ float2 sred[4][64];
  f32x4 acc[4][4];
  #pragma unroll
  for (int i = 0; i < 4; ++i)
    #pragma unroll
    for (int j = 0; j < 4; ++j) acc[i][j] = (f32x4){0.f, 0.f, 0.f, 0.f};

  for (int c0 = 0; c0 < 256; c0 += 32) {
    __syncthreads();
    for (int i = t; i < 1024; i += 256) {
      const int cell = i >> 2, part = i & 3;
      const int gy = ty0 + (cell >> 4), gx = tx0 + (cell & 15);
      *(f16x8*)&at[cell][part * 8] =
          *(const f16x8*)&x[(((size_t)bb * H + gy) * W + gx) * 256 + c0 + part * 8];
    }
    {
      const int i = t;
      const int co = i >> 2, part = i & 3;
      *(f16x8*)&btw[co][part * 8] =
          *(const f16x8*)&wtp[((size_t)par * 256 + co0 + co) * 256 + c0 + part * 8];
    }
    __syncthreads();
    f16x8 af[4], bf[4];
    #pragma unroll
    for (int fm = 0; fm < 4; ++fm)
      af[fm] = *(const f16x8*)&at[wv * 64 + fm * 16 + frow][kg * 8];
    #pragma unroll
    for (int fn = 0; fn < 4; ++fn)
      bf[fn] = *(const f16x8*)&btw[fn * 16 + frow][kg * 8];
    #pragma unroll
    for (int fm = 0; fm < 4; ++fm)
      #pragma unroll
      for (int fn = 0; fn < 4; ++fn)
        acc[fm][fn] = __builtin_amdgcn_mfma_f32_16x16x32_f16(af[fm], bf[fn], acc[fm][fn], 0, 0, 0);
  }
  const int HO = H << 1, WO = W << 1;
  float ps[4] = {0.f, 0.f, 0.f, 0.f}, ss[4] = {0.f, 0.f, 0.f, 0.f};
  #pragma unroll
  for (int fn = 0; fn < 4; ++fn) {
    const int col = co0 + fn * 16 + frow;
    const float bv = bias[col];
    #pragma unroll
    for (int fm = 0; fm < 4; ++fm)
      #pragma unroll
      for (int r = 0; r < 4; ++r) {
        const int pos = wv * 64 + fm * 16 + kg * 4 + r;
        const int oy = ((ty0 + (pos >> 4)) << 1) + pa;
        const int ox = ((tx0 + (pos & 15)) << 1) + pb;
        const float v = acc[fm][fn][r] + bv;
        ps[fn] += v; ss[fn] += v * v;
        y[(((size_t)bb * HO + oy) * WO + ox) * 256 + col] = (f16)v;
      }
  }
  #pragma unroll
  for (int fn = 0; fn < 4; ++fn)
    #pragma unroll
    for (int msk = 16; msk < 64; msk <<= 1) {
      ps[fn] += __shfl_xor(ps[fn], msk);
      ss[fn] += __shfl_xor(ss[fn], msk);
    }
  __syncthreads();
  if (kg == 0) {
    #pragma unroll
    for (int fn = 0; fn < 4; ++fn) sred[wv][fn * 16 + frow] = make_float2(ps[fn], ss[fn]);
  }
  __syncthreads();
  if (t < 64) {
    float a1 = 0.f, a2 = 0.f;
    #pragma unroll
    for (int w = 0; w < 4; ++w) { a1 += sred[w][t].x; a2 += sred[w][t].y; }
    partial[((size_t)bb * 256 + blockIdx.x * 4 + par) * 256 + co0 + t] = make_float2(a1, a2);
  }
}

// ---------------------------------------------------------------- stats2 (runtime NS, parallel)
__global__ __launch_bounds__(256) void stats2v2_k(
    const float2* __restrict__ partial, float2* __restrict__ mr, int HW, int NS)
{
  const int cg = blockIdx.x, b = blockIdx.y, t = threadIdx.x;
  const int chl = t & 31, g = t >> 5;
  const int ch = cg * 32 + chl;
  float s1 = 0.f, s2 = 0.f;
  for (int s = g; s < NS; s += 8) {
    const float2 v = partial[((size_t)b * 256 + s) * 256 + ch];
    s1 += v.x; s2 += v.y;
  }
  __shared__ float r1[8][32], r2[8][32];
  r1[g][chl] = s1; r2[g][chl] = s2;
  __syncthreads();
  if (t < 32) {
    float a1 = 0.f, a2 = 0.f;
    #pragma unroll
    for (int gg = 0; gg < 8; ++gg) { a1 += r1[gg][t]; a2 += r2[gg][t]; }
    const float m = a1 / (float)HW;
    const float var = fmaxf(a2 / (float)HW - m * m, 0.f);
    mr[b * 256 + cg * 32 + t] = make_float2(m, rsqrtf(var + 1e-5f));
  }
}

// ---------------------------------------------------------------- vectorized normalize+leaky
__global__ __launch_bounds__(256) void norm8_k(
    f16* __restrict__ x, const float2* __restrict__ mr, int HW)
{
  const int b = blockIdx.y, t = threadIdx.x;
  const int cp = t & 31, rg = t >> 5;
  float2 mv[8];
  {
    const float2* mrb = mr + b * 256 + cp * 8;
    #pragma unroll
    for (int j = 0; j < 8; ++j) mv[j] = mrb[j];
  }
  f16* p = x + ((size_t)b * HW + (size_t)blockIdx.x * 64) * 256 + cp * 8;
  #pragma unroll
  for (int r8 = 0; r8 < 8; ++r8) {
    const int r = rg + r8 * 8;
    f16x8 v = *(const f16x8*)&p[(size_t)r * 256];
    #pragma unroll
    for (int j = 0; j < 8; ++j) {
      const float z = ((float)v[j] - mv[j].x) * mv[j].y;
      v[j] = (f16)(z >= 0.f ? z : 0.01f * z);
    }
    *(f16x8*)&p[(size_t)r * 256] = v;
  }
}

// ---------------------------------------------------------------- MFMA out conv 3x3; weights direct
__global__ __launch_bounds__(256) void convoutm2_k(
    const f16* __restrict__ x, const f16* __restrict__ wocp, const float* __restrict__ bias,
    void* __restrict__ yv, const int* __restrict__ flags)
{
  const int ty0 = (blockIdx.x >> 4) << 4, tx0 = (blockIdx.x & 15) << 4;
  const int b = blockIdx.y;
  const int t = threadIdx.x;
  const int lane = t & 63, wv = t >> 6;
  const int frow = lane & 15, kg = lane >> 4;
  __shared__ f16 halo[18][18][40];
  f32x4 acc[4];
  #pragma unroll
  for (int i = 0; i < 4; ++i) acc[i] = (f32x4){0.f, 0.f, 0.f, 0.f};

  for (int c0 = 0; c0 < 256; c0 += 32) {
    __syncthreads();
    for (int i = t; i < 1296; i += 256) {
      const int cell = i >> 2, part = i & 3;
      const int hy = cell / 18, hx = cell - hy * 18;
      const int gy = ty0 + hy - 1, gx = tx0 + hx - 1;
      f16x8 v = {(f16)0,(f16)0,(f16)0,(f16)0,(f16)0,(f16)0,(f16)0,(f16)0};
      if ((unsigned)gy < 256u && (unsigned)gx < 256u)
        v = *(const f16x8*)&x[(((size_t)b * 256 + gy) * 256 + gx) * 256 + c0 + part * 8];
      *(f16x8*)&halo[hy][hx][part * 8] = v;
    }
    __syncthreads();
    #pragma unroll
    for (int kyr = 0; kyr < 3; ++kyr)
      #pragma unroll
      for (int kx = 0; kx < 3; ++kx) {
        const int tap = kyr * 3 + kx;
        const f16x8 bf = *(const f16x8*)&wocp[((size_t)(tap * 16 + frow)) * 256 + c0 + kg * 8];
        #pragma unroll
        for (int fm = 0; fm < 4; ++fm) {
          const int pos = wv * 64 + fm * 16 + frow;
          const f16x8 af = *(const f16x8*)&halo[(pos >> 4) + kyr][(pos & 15) + kx][kg * 8];
          acc[fm] = __builtin_amdgcn_mfma_f32_16x16x32_f16(af, bf, acc[fm], 0, 0, 0);
        }
      }
  }
  if (frow < 3) {
    const int fp32 = flags[0];
    const float bv = bias[frow];
    #pragma unroll
    for (int fm = 0; fm < 4; ++fm)
      #pragma unroll
      for (int r = 0; r < 4; ++r) {
        const int pos = wv * 64 + fm * 16 + kg * 4 + r;
        const int oy = ty0 + (pos >> 4), ox = tx0 + (pos & 15);
        const size_t oidx = (((size_t)b * 3 + frow) * 256 + oy) * 256 + ox;
        const float v = acc[fm][r] + bv;
        if (fp32) ((float*)yv)[oidx] = v;
        else      ((bf16*)yv)[oidx] = __float2bfloat16(v);
      }
  }
}

// ================================================================ host
extern "C" void kernel_launch(void* const* d_in, const int* in_sizes, int n_in,
                              void* d_out, int out_size, void* d_ws, size_t ws_size,
                              hipStream_t stream) {
  (void)in_sizes; (void)n_in; (void)out_size; (void)ws_size;
  const int* pc = (const int*)d_in[1];

  float* P = (float*)d_ws;
  size_t off = 0;
  CvtDesc cd{};
  int seg = 0;
  auto alloc = [&](size_t n) { float* p = P + off; off += n; return p; };
  auto allocCv = [&](int idx, size_t n) {
    float* p = P + off;
    cd.src[seg] = d_in[idx]; cd.dstOff[seg] = (unsigned)off; cd.n[seg] = (unsigned)n;
    ++seg; off += n; return p;
  };

  // ---- persistent small region ----
  int*    flags   = (int*)alloc(16);
  int*    invbuf  = (int*)alloc(1024);
  float2* partial = (float2*)alloc(262144);
  float2* mr1     = (float2*)alloc(1024);
  float* pdb   = allocCv(3, 256);
  float* pw1   = allocCv(4, 512);
  float* pb1   = allocCv(5, 256);
  float* pb2   = allocCv(7, 256);
  float* pln1g = allocCv(9, 512);
  float* pln1b = allocCv(10, 512);
  float* pqkvb = allocCv(12, 1536);
  float* pattb = allocCv(14, 512);
  float* pln2g = allocCv(15, 512);
  float* pln2b = allocCv(16, 512);
  float* pm1b  = allocCv(18, 2048);
  float* pm2b  = allocCv(20, 512);
  float* pdecg = allocCv(21, 256);
  float* pdecb = allocCv(22, 256);
  float* pmg   = allocCv(25, 256);
  float* pmb   = allocCv(26, 256);
  float* pucb  = allocCv(28, 768);
  float* putb  = allocCv(30, 768);
  float* pocw  = allocCv(31, 6912);
  float* pocb  = allocCv(32, 16);
  off = (off + 255) & ~(size_t)255;
  f16* wf3  = (f16*)alloc(884736);
  f16* wt   = (f16*)alloc(393216);
  f16* wocp = (f16*)alloc(18432);
  off = (off + 255) & ~(size_t)255;

  // ---- zone A: big fp32 params + transformer scratch, later overlaid by R2 (f16) ----
  float* zoneA = P + off;
  f16*   R2h   = (f16*)zoneA;
  {
    size_t zo = off;
    auto zCv = [&](int idx, size_t n) {
      float* p = P + zo;
      cd.src[seg] = d_in[idx]; cd.dstOff[seg] = (unsigned)zo; cd.n[seg] = (unsigned)n;
      ++seg; zo += n; return p;
    };
    float* px    = zCv(0, 655360);
    float* pdw   = zCv(2, 131072);
    float* pw2   = zCv(6, 65536);
    float* pcls  = zCv(8, 65536);
    float* pqkvw = zCv(11, 393216);
    float* pattw = zCv(13, 131072);
    float* pm1w  = zCv(17, 524288);
    float* pm2w  = zCv(19, 524288);
    float* pprp  = zCv(23, 65536);
    float* pprc  = zCv(24, 65536);
    float* pucw  = zCv(27, 1769472);
    float* putw  = zCv(29, 786432);
    float* xbuf   = P + zo; zo += 458752;
    float* hbuf   = P + zo; zo += 458752;
    float* qkvbuf = P + zo; zo += 1376256;
    float* hidbuf = P + zo; zo += 1835008;
    float* posbuf = P + zo; zo += 163840;
    float* patbuf = P + zo; zo += 327680;
    float* clsbuf = P + zo; zo += 131072;
    float* masksb = P + zo; zo += 327680;
    off += 16777216;
    f16* R0h = (f16*)(P + off); off += 4194304;
    f16* R1h = (f16*)(P + off); off += 4194304;

    // 0) detect dtype, convert inputs to fp32, prep conv weights
    detect_k<<<1, 64, 0, stream>>>((const unsigned short*)d_in[0], flags);
    cvtall_k<<<dim3(256, NSEG), 256, 0, stream>>>(cd, P, flags);
    prepw_k<<<2048, 256, 0, stream>>>(pucw, putw, pocw, wf3, wt, wocp);

    // 1) positional MLP + projection + assembly
    posh_k<<<640, 256, 0, stream>>>(pc, pw1, pb1, patbuf);
    gemm64_k<false, 0><<<dim3(4, 10), 256, 0, stream>>>(
        patbuf, pw2, pb2, nullptr, posbuf, 640, 256, 256);
    gemm64_k<false, 0><<<dim3(4, 20), 256, 0, stream>>>(
        px, pdw, pdb, nullptr, hidbuf, 1280, 256, 512);
    assemble_k<<<1792, 256, 0, stream>>>(hidbuf, posbuf, pcls, xbuf);

    // 2) transformer blocks
    for (int l = 0; l < 2; ++l) {
      ln_k<<<1792, 256, 0, stream>>>(xbuf, hbuf, pln1g + l * 256, pln1b + l * 256);
      gemm64_k<false, 0><<<dim3(12, 28), 256, 0, stream>>>(
          hbuf, pqkvw + (size_t)l * 196608, pqkvb + l * 768, nullptr, qkvbuf, 1792, 768, 256);
      attnm_k<<<dim3(28, 8, 2), 128, 0, stream>>>(qkvbuf, hbuf);
      gemm64_k<false, 0><<<dim3(4, 28), 256, 0, stream>>>(
          hbuf, pattw + (size_t)l * 65536, pattb + l * 256, xbuf, xbuf, 1792, 256, 256);
      ln_k<<<1792, 256, 0, stream>>>(xbuf, hbuf, pln2g + l * 256, pln2b + l * 256);
      gemm64_k<false, 1><<<dim3(16, 28), 256, 0, stream>>>(
          hbuf, pm1w + (size_t)l * 262144, pm1b + l * 1024, nullptr, hidbuf, 1792, 1024, 256);
      gemm64_k<false, 0><<<dim3(4, 28), 256, 0, stream>>>(
          hidbuf, pm2w + (size_t)l * 262144, pm2b + l * 256, xbuf, xbuf, 1792, 256, 1024);
    }

    // 3) decoder head
    ln_k<<<1792, 256, 0, stream>>>(xbuf, hbuf, pdecg, pdecb);
    for (int b = 0; b < 2; ++b) {
      gemm64_k<false, 0><<<dim3(4, 10), 256, 0, stream>>>(
          hbuf + (size_t)b * 896 * 256, pprp, nullptr, nullptr,
          patbuf + (size_t)b * 640 * 256, 640, 256, 256);
      gemm64_k<false, 0><<<dim3(4, 4), 256, 0, stream>>>(
          hbuf + ((size_t)b * 896 + 640) * 256, pprc, nullptr, nullptr,
          clsbuf + (size_t)b * 65536, 256, 256, 256);
    }
    l2n_k<<<1280, 256, 0, stream>>>(patbuf);
    l2n_k<<<512, 256, 0, stream>>>(clsbuf);
    for (int b = 0; b < 2; ++b) {
      gemm64_k<true, 0><<<dim3(4, 10), 256, 0, stream>>>(
          patbuf + (size_t)b * 163840, clsbuf + (size_t)b * 65536, nullptr, nullptr,
          masksb + (size_t)b * 163840, 640, 256, 256);
    }
    ln_k<<<1280, 256, 0, stream>>>(masksb, masksb, pmg, pmb);

    // 4) scatter table + gather
    inv_k<<<1, 1024, 0, stream>>>(pc, invbuf);
    gather16_k<<<2048, 256, 0, stream>>>(masksb, invbuf, R0h);

    // 5) MFMA conv decoder: fused stats epilogue + separate norm pass
    int H = 32;
    for (int i = 0; i < 3; ++i) {
      const int tiles = (H / 16) * (H / 16);
      conv3m_k<<<dim3(tiles, 4, 2), 256, 0, stream>>>(
          R0h, wf3 + (size_t)i * 9 * 65536, pucb + i * 256, R1h, H, H, partial);
      stats2v2_k<<<dim3(8, 2), 256, 0, stream>>>(partial, mr1, H * H, tiles);
      norm8_k<<<dim3(H * H / 64, 2), 256, 0, stream>>>(R1h, mr1, H * H);
      f16* dst = (i == 2) ? R2h : R0h;
      convtm_k<<<dim3(tiles, 16, 2), 256, 0, stream>>>(
          R1h, wt + (size_t)i * 4 * 65536, putb + i * 256, dst, H, H, partial);
      stats2v2_k<<<dim3(8, 2), 256, 0, stream>>>(partial, mr1, 4 * H * H, tiles * 4);
      norm8_k<<<dim3(4 * H * H / 64, 2), 256, 0, stream>>>(dst, mr1, 4 * H * H);
      H *= 2;
    }

    // 6) output conv 256 -> 3 via MFMA (reads pre-normalized R2)
    convoutm2_k<<<dim3(256, 2), 256, 0, stream>>>(R2h, wocp, pocb, d_out, flags);
  }
}

// Round 18
// 627.587 us; speedup vs baseline: 1.1011x; 1.0253x over previous
//
#include <hip/hip_runtime.h>
#include <hip/hip_bf16.h>

typedef __hip_bfloat16 bf16;
typedef _Float16 f16;
typedef __attribute__((ext_vector_type(8))) _Float16 f16x8;
typedef __attribute__((ext_vector_type(4))) float f32x4;

// ---------------------------------------------------------------- dtype detector (wave-parallel)
__global__ void detect_k(const unsigned short* __restrict__ xh, int* __restrict__ flags)
{
  const int t = threadIdx.x;   // 64
  int w = 0;
  for (int i = t; i < 512; i += 64) {
    const int e = (xh[i] >> 7) & 0xFF;
    if (e == 0xFF || e >= 0x88) ++w;
  }
  #pragma unroll
  for (int msk = 1; msk < 64; msk <<= 1) w += __shfl_xor(w, msk);
  if (t == 0) flags[0] = (w > 32) ? 1 : 0;
}

// ---------------------------------------------------------------- batched input->fp32 convert
#define NSEG 33
struct CvtDesc {
  const void* src[NSEG];
  unsigned dstOff[NSEG];
  unsigned n[NSEG];
};
__global__ __launch_bounds__(256) void cvtall_k(
    CvtDesc d, float* __restrict__ P, const int* __restrict__ flags)
{
  const int s = blockIdx.y;
  const unsigned n = d.n[s];
  const int fp32 = flags[0];
  float* dst = P + d.dstOff[s];
  const unsigned stride = gridDim.x * 256u;
  if (fp32) {
    const float* src = (const float*)d.src[s];
    for (unsigned i = blockIdx.x * 256u + threadIdx.x; i < n; i += stride) dst[i] = src[i];
  } else {
    const bf16* src = (const bf16*)d.src[s];
    for (unsigned i = blockIdx.x * 256u + threadIdx.x; i < n; i += stride)
      dst[i] = __bfloat162float(src[i]);
  }
}

// ---------------------------------------------------------------- conv weight prep
__global__ __launch_bounds__(256) void prepw_k(
    const float* __restrict__ ucw, const float* __restrict__ utw, const float* __restrict__ ocw,
    f16* __restrict__ wf3, f16* __restrict__ wt, f16* __restrict__ wocp)
{
  const int n1 = 3 * 9 * 65536;
  const int n2 = 3 * 4 * 65536;
  const int n3 = 9 * 16 * 256;
  for (int i = blockIdx.x * 256 + threadIdx.x; i < n1 + n2 + n3; i += gridDim.x * 256) {
    if (i < n1) {
      const int st = i / 589824, r = i % 589824;
      const int kk = r / 65536, rr = r % 65536;
      const int co = rr >> 8, ci = rr & 255;
      wf3[i] = (f16)ucw[(((size_t)st * 256 + co) * 256 + ci) * 9 + kk];
    } else if (i < n1 + n2) {
      const int j = i - n1;
      const int st = j / 262144, r = j % 262144;
      const int ij = r / 65536, rr = r % 65536;
      const int co = rr >> 8, ci = rr & 255;
      wt[j] = (f16)utw[(((size_t)st * 256 + ci) * 256 + co) * 4 + ij];
    } else {
      const int j = i - n1 - n2;
      const int tap = j >> 12, rem = j & 4095;
      const int co = rem >> 8, ci = rem & 255;
      wocp[j] = (co < 3) ? (f16)ocw[(((size_t)co * 256) + ci) * 9 + tap] : (f16)0.f;
    }
  }
}

// ---------------------------------------------------------------- MFMA GEMM 64x64 tile, 4 waves
// optional z-batching: A/B/C advance by zA/zB/zC elements per blockIdx.z
template<bool TRB, int ACT>
__global__ __launch_bounds__(256) void gemm64_k(
    const float* __restrict__ A, const float* __restrict__ B,
    const float* __restrict__ bias, const float* __restrict__ res,
    float* __restrict__ C, int M, int N, int K,
    size_t zA, size_t zB, size_t zC)
{
  A += (size_t)blockIdx.z * zA;
  B += (size_t)blockIdx.z * zB;
  C += (size_t)blockIdx.z * zC;
  const int m0 = blockIdx.y << 6, n0 = blockIdx.x << 6;
  const int t = threadIdx.x;
  const int lane = t & 63, wv = t >> 6;
  const int wm = wv >> 1, wn = wv & 1;
  const int frow = lane & 15, kg = lane >> 4;
  __shared__ f16 As[64][40];
  __shared__ f16 Bs[64][40];
  f32x4 acc[2][2];
  #pragma unroll
  for (int i = 0; i < 2; ++i)
    #pragma unroll
    for (int j = 0; j < 2; ++j) acc[i][j] = (f32x4){0.f, 0.f, 0.f, 0.f};

  for (int k0 = 0; k0 < K; k0 += 32) {
    __syncthreads();
    {
      const int row = t >> 2, kh = (t & 3) << 3;
      const float* ap = A + (size_t)(m0 + row) * K + k0 + kh;
      #pragma unroll
      for (int j = 0; j < 8; ++j) As[row][kh + j] = (f16)ap[j];
    }
    if (TRB) {
      const int row = t >> 2, kh = (t & 3) << 3;
      const float* bp = B + (size_t)(n0 + row) * K + k0 + kh;
      #pragma unroll
      for (int j = 0; j < 8; ++j) Bs[row][kh + j] = (f16)bp[j];
    } else {
      #pragma unroll
      for (int i2 = 0; i2 < 8; ++i2) {
        const int i = i2 * 256 + t;
        const int n = i & 63, kk = i >> 6;
        Bs[n][kk] = (f16)B[(size_t)(k0 + kk) * N + n0 + n];
      }
    }
    __syncthreads();
    f16x8 af[2], bf[2];
    #pragma unroll
    for (int fm = 0; fm < 2; ++fm)
      af[fm] = *(const f16x8*)&As[wm * 32 + fm * 16 + frow][kg * 8];
    #pragma unroll
    for (int fn = 0; fn < 2; ++fn)
      bf[fn] = *(const f16x8*)&Bs[wn * 32 + fn * 16 + frow][kg * 8];
    #pragma unroll
    for (int fm = 0; fm < 2; ++fm)
      #pragma unroll
      for (int fn = 0; fn < 2; ++fn)
        acc[fm][fn] = __builtin_amdgcn_mfma_f32_16x16x32_f16(af[fm], bf[fn], acc[fm][fn], 0, 0, 0);
  }
  #pragma unroll
  for (int fn = 0; fn < 2; ++fn) {
    const int col = n0 + wn * 32 + fn * 16 + frow;
    const float bv = bias ? bias[col] : 0.f;
    #pragma unroll
    for (int fm = 0; fm < 2; ++fm)
      #pragma unroll
      for (int r = 0; r < 4; ++r) {
        const int row = m0 + wm * 32 + fm * 16 + kg * 4 + r;
        float v = acc[fm][fn][r] + bv;
        if (ACT == 1) v = 0.5f * v * (1.0f + erff(v * 0.70710678118654752f));
        if (res) v += res[(size_t)row * N + col];
        C[(size_t)row * N + col] = v;
      }
  }
}

// ---------------------------------------------------------------- LayerNorm (row len 256, shfl reduce)
__global__ __launch_bounds__(256) void ln_k(
    const float* __restrict__ in, float* __restrict__ out,
    const float* __restrict__ g, const float* __restrict__ b)
{
  const int row = blockIdx.x, t = threadIdx.x;
  __shared__ float ws1[4], ws2[4];
  const float x = in[(size_t)row * 256 + t];
  float v = x;
  #pragma unroll
  for (int msk = 1; msk < 64; msk <<= 1) v += __shfl_xor(v, msk);
  if ((t & 63) == 0) ws1[t >> 6] = v;
  __syncthreads();
  const float m = (ws1[0] + ws1[1] + ws1[2] + ws1[3]) * (1.0f / 256.0f);
  const float d = x - m;
  float v2 = d * d;
  #pragma unroll
  for (int msk = 1; msk < 64; msk <<= 1) v2 += __shfl_xor(v2, msk);
  if ((t & 63) == 0) ws2[t >> 6] = v2;
  __syncthreads();
  const float rstd = rsqrtf((ws2[0] + ws2[1] + ws2[2] + ws2[3]) * (1.0f / 256.0f) + 1e-5f);
  out[(size_t)row * 256 + t] = d * rstd * g[t] + b[t];
}

// ---------------------------------------------------------------- L2 normalize rows (shfl reduce)
__global__ __launch_bounds__(256) void l2n_k(float* __restrict__ x)
{
  const int row = blockIdx.x, t = threadIdx.x;
  __shared__ float ws[4];
  const float v = x[(size_t)row * 256 + t];
  float s = v * v;
  #pragma unroll
  for (int msk = 1; msk < 64; msk <<= 1) s += __shfl_xor(s, msk);
  if ((t & 63) == 0) ws[t >> 6] = s;
  __syncthreads();
  x[(size_t)row * 256 + t] = v * rsqrtf(ws[0] + ws[1] + ws[2] + ws[3]);
}

// ---------------------------------------------------------------- pos hidden (elementwise)
__global__ __launch_bounds__(256) void posh_k(
    const int* __restrict__ pc, const float* __restrict__ w1, const float* __restrict__ b1,
    float* __restrict__ hid)
{
  const int n = blockIdx.x, t = threadIdx.x;
  const int wide = (pc[3] == 0);
  const int sv = wide ? pc[4 * n] : pc[2 * n];
  const int cv = wide ? pc[4 * n + 2] : pc[2 * n + 1];
  const float hv = (float)sv * w1[t] + (float)cv * w1[256 + t] + b1[t];
  hid[(size_t)n * 256 + t] = hv > 0.0f ? hv : 0.0f;
}

// ---------------------------------------------------------------- assemble x = [proj+pos ; cls]
__global__ __launch_bounds__(256) void assemble_k(
    const float* __restrict__ proj, const float* __restrict__ pos,
    const float* __restrict__ cls, float* __restrict__ xb)
{
  const int row = blockIdx.x;
  const int b = row / 896, n = row % 896, t = threadIdx.x;
  float v;
  if (n < 640) v = proj[((size_t)b * 640 + n) * 256 + t] + pos[n * 256 + t];
  else         v = cls[(n - 640) * 256 + t];
  xb[(size_t)row * 256 + t] = v;
}

// ---------------------------------------------------------------- MFMA flash attention
__global__ __launch_bounds__(128) void attnm_k(
    const float* __restrict__ qkv, float* __restrict__ out)
{
  const int q0 = blockIdx.x << 5;
  const int h = blockIdx.y, b = blockIdx.z;
  const int t = threadIdx.x;
  const int lane = t & 63, wv = t >> 6;
  const int c = lane & 15, kg = lane >> 4;
  __shared__ f16 Qs[32][36];
  __shared__ f16 Ks[64][36];
  __shared__ f16 Vt[32][68];
  __shared__ f16 Pl[2][16][68];
  {
    const int row = t >> 2, part = t & 3;
    const float* src = qkv + ((size_t)(b * 896 + q0 + row) * 768) + h * 32 + part * 8;
    f16 tmp[8];
    #pragma unroll
    for (int j = 0; j < 8; ++j) tmp[j] = (f16)(src[j] * 0.17677669529663687f);
    *(f16x8*)&Qs[row][part * 8] = *(const f16x8*)tmp;
  }
  const f32x4 z4 = {0.f, 0.f, 0.f, 0.f};
  f32x4 o0 = z4, o1 = z4;
  float m[4] = {-1e30f, -1e30f, -1e30f, -1e30f};
  float l[4] = {0.f, 0.f, 0.f, 0.f};

  for (int k0 = 0; k0 < 896; k0 += 64) {
    __syncthreads();
    for (int i = t; i < 256; i += 128) {
      const int row = i >> 2, part = i & 3;
      const float* src = qkv + ((size_t)(b * 896 + k0 + row) * 768) + 256 + h * 32 + part * 8;
      f16 tmp[8];
      #pragma unroll
      for (int j = 0; j < 8; ++j) tmp[j] = (f16)src[j];
      *(f16x8*)&Ks[row][part * 8] = *(const f16x8*)tmp;
    }
    for (int i = t; i < 256; i += 128) {
      const int row = i >> 2, part = i & 3;
      const float* src = qkv + ((size_t)(b * 896 + k0 + row) * 768) + 512 + h * 32 + part * 8;
      #pragma unroll
      for (int j = 0; j < 8; ++j) Vt[part * 8 + j][row] = (f16)src[j];
    }
    __syncthreads();
    const f16x8 aq = *(const f16x8*)&Qs[wv * 16 + c][kg * 8];
    f32x4 s[4];
    #pragma unroll
    for (int fn = 0; fn < 4; ++fn)
      s[fn] = __builtin_amdgcn_mfma_f32_16x16x32_f16(
          aq, *(const f16x8*)&Ks[fn * 16 + c][kg * 8], z4, 0, 0, 0);
    float sc[4];
    #pragma unroll
    for (int r = 0; r < 4; ++r) {
      float v = fmaxf(fmaxf(s[0][r], s[1][r]), fmaxf(s[2][r], s[3][r]));
      #pragma unroll
      for (int msk = 1; msk < 16; msk <<= 1) v = fmaxf(v, __shfl_xor(v, msk));
      const float mn = fmaxf(m[r], v);
      sc[r] = __expf(m[r] - mn);
      m[r] = mn;
    }
    #pragma unroll
    for (int r = 0; r < 4; ++r) {
      float ps = 0.f;
      #pragma unroll
      for (int fn = 0; fn < 4; ++fn) {
        const float p = __expf(s[fn][r] - m[r]);
        ps += p;
        Pl[wv][kg * 4 + r][fn * 16 + c] = (f16)p;
      }
      #pragma unroll
      for (int msk = 1; msk < 16; msk <<= 1) ps += __shfl_xor(ps, msk);
      l[r] = l[r] * sc[r] + ps;
    }
    #pragma unroll
    for (int r = 0; r < 4; ++r) { o0[r] *= sc[r]; o1[r] *= sc[r]; }
    const f16x8 a0 = *(const f16x8*)&Pl[wv][c][kg * 8];
    const f16x8 a1 = *(const f16x8*)&Pl[wv][c][32 + kg * 8];
    o0 = __builtin_amdgcn_mfma_f32_16x16x32_f16(a0, *(const f16x8*)&Vt[c][kg * 8], o0, 0, 0, 0);
    o0 = __builtin_amdgcn_mfma_f32_16x16x32_f16(a1, *(const f16x8*)&Vt[c][32 + kg * 8], o0, 0, 0, 0);
    o1 = __builtin_amdgcn_mfma_f32_16x16x32_f16(a0, *(const f16x8*)&Vt[16 + c][kg * 8], o1, 0, 0, 0);
    o1 = __builtin_amdgcn_mfma_f32_16x16x32_f16(a1, *(const f16x8*)&Vt[16 + c][32 + kg * 8], o1, 0, 0, 0);
  }
  #pragma unroll
  for (int r = 0; r < 4; ++r) {
    const int row = q0 + wv * 16 + kg * 4 + r;
    const float inv = 1.0f / l[r];
    out[((size_t)(b * 896 + row) * 256) + h * 32 + c] = o0[r] * inv;
    out[((size_t)(b * 896 + row) * 256) + h * 32 + 16 + c] = o1[r] * inv;
  }
}

// ---------------------------------------------------------------- build inv table
__global__ __launch_bounds__(1024) void inv_k(const int* __restrict__ pc, int* __restrict__ inv)
{
  const int t = threadIdx.x;
  if (t < 1024) inv[t] = 0;
  __syncthreads();
  if (t < 640) {
    const int wide = (pc[3] == 0);
    int s = wide ? pc[4 * t] : pc[2 * t];
    int coord = wide ? pc[4 * t + 2] : pc[2 * t + 1];
    s &= 1;
    const int gs = 16 << s;
    const int k = 1 << (1 - s);
    const int r = (coord / gs) * k, c = (coord % gs) * k;
    for (int oi = 0; oi < k; ++oi)
      for (int oj = 0; oj < k; ++oj) {
        const int rr = r + oi, cc = c + oj;
        if (rr >= 0 && rr < 32 && cc >= 0 && cc < 32)
          inv[rr * 32 + cc] = t;
      }
  }
}

// ---------------------------------------------------------------- gather masks -> NHWC f16 img
__global__ __launch_bounds__(256) void gather16_k(
    const float* __restrict__ masks, const int* __restrict__ inv, f16* __restrict__ img)
{
  const int p = blockIdx.x & 1023, b = blockIdx.x >> 10, t = threadIdx.x;
  img[((size_t)blockIdx.x << 8) + t] = (f16)masks[((size_t)b * 640 + inv[p]) * 256 + t];
}

// ---------------------------------------------------------------- MFMA conv3x3 (64-co, bt9 staged)
// fused per-channel stats epilogue -> partial[b][tile][256]
__global__ __launch_bounds__(256) void conv3m_k(
    const f16* __restrict__ x, const f16* __restrict__ wf, const float* __restrict__ bias,
    f16* __restrict__ y, int H, int W, float2* __restrict__ partial)
{
  const int tilesx = W >> 4;
  const int ty0 = (blockIdx.x / tilesx) << 4, tx0 = (blockIdx.x % tilesx) << 4;
  const int co0 = blockIdx.y << 6;
  const int bb = blockIdx.z;
  const int t = threadIdx.x;
  const int lane = t & 63, wv = t >> 6;
  const int frow = lane & 15, kg = lane >> 4;
  __shared__ f16 halo[18][18][40];
  __shared__ f16 bt9[9][64][40];
  __shared__ float2 sred[4][64];
  f32x4 acc[4][4];
  #pragma unroll
  for (int i = 0; i < 4; ++i)
    #pragma unroll
    for (int j = 0; j < 4; ++j) acc[i][j] = (f32x4){0.f, 0.f, 0.f, 0.f};

  for (int c0 = 0; c0 < 256; c0 += 32) {
    __syncthreads();
    for (int i = t; i < 1296; i += 256) {
      const int cell = i >> 2, part = i & 3;
      const int hy = cell / 18, hx = cell - hy * 18;
      const int gy = ty0 + hy - 1, gx = tx0 + hx - 1;
      f16x8 v = {(f16)0,(f16)0,(f16)0,(f16)0,(f16)0,(f16)0,(f16)0,(f16)0};
      if (gy >= 0 && gy < H && gx >= 0 && gx < W)
        v = *(const f16x8*)&x[(((size_t)bb * H + gy) * W + gx) * 256 + c0 + part * 8];
      *(f16x8*)&halo[hy][hx][part * 8] = v;
    }
    for (int i = t; i < 2304; i += 256) {
      const int tap = i >> 8, rem = i & 255, co = rem >> 2, part = rem & 3;
      *(f16x8*)&bt9[tap][co][part * 8] =
          *(const f16x8*)&wf[(((size_t)tap * 256) + co0 + co) * 256 + c0 + part * 8];
    }
    __syncthreads();
    #pragma unroll
    for (int kyr = 0; kyr < 3; ++kyr)
      #pragma unroll
      for (int kx = 0; kx < 3; ++kx) {
        f16x8 af[4], bf[4];
        #pragma unroll
        for (int fm = 0; fm < 4; ++fm) {
          const int pos = wv * 64 + fm * 16 + frow;
          af[fm] = *(const f16x8*)&halo[(pos >> 4) + kyr][(pos & 15) + kx][kg * 8];
        }
        #pragma unroll
        for (int fn = 0; fn < 4; ++fn)
          bf[fn] = *(const f16x8*)&bt9[kyr * 3 + kx][fn * 16 + frow][kg * 8];
        #pragma unroll
        for (int fm = 0; fm < 4; ++fm)
          #pragma unroll
          for (int fn = 0; fn < 4; ++fn)
            acc[fm][fn] = __builtin_amdgcn_mfma_f32_16x16x32_f16(af[fm], bf[fn], acc[fm][fn], 0, 0, 0);
      }
  }
  float ps[4] = {0.f, 0.f, 0.f, 0.f}, ss[4] = {0.f, 0.f, 0.f, 0.f};
  #pragma unroll
  for (int fn = 0; fn < 4; ++fn) {
    const int col = co0 + fn * 16 + frow;
    const float bv = bias[col];
    #pragma unroll
    for (int fm = 0; fm < 4; ++fm)
      #pragma unroll
      for (int r = 0; r < 4; ++r) {
        const int pos = wv * 64 + fm * 16 + kg * 4 + r;
        const float v = acc[fm][fn][r] + bv;
        ps[fn] += v; ss[fn] += v * v;
        y[(((size_t)bb * H + ty0 + (pos >> 4)) * W + tx0 + (pos & 15)) * 256 + col] = (f16)v;
      }
  }
  #pragma unroll
  for (int fn = 0; fn < 4; ++fn)
    #pragma unroll
    for (int msk = 16; msk < 64; msk <<= 1) {
      ps[fn] += __shfl_xor(ps[fn], msk);
      ss[fn] += __shfl_xor(ss[fn], msk);
    }
  __syncthreads();
  if (kg == 0) {
    #pragma unroll
    for (int fn = 0; fn < 4; ++fn) sred[wv][fn * 16 + frow] = make_float2(ps[fn], ss[fn]);
  }
  __syncthreads();
  if (t < 64) {
    float a1 = 0.f, a2 = 0.f;
    #pragma unroll
    for (int w = 0; w < 4; ++w) { a1 += sred[w][t].x; a2 += sred[w][t].y; }
    partial[((size_t)bb * 256 + blockIdx.x) * 256 + co0 + t] = make_float2(a1, a2);
  }
}

// ---------------------------------------------------------------- MFMA convT 2x2 s2 (staged weights)
// fused stats epilogue -> partial[b][tile*4+par][256]
__global__ __launch_bounds__(256) void convtm_k(
    const f16* __restrict__ x, const f16* __restrict__ wtp, const float* __restrict__ bias,
    f16* __restrict__ y, int H, int W, float2* __restrict__ partial)
{
  const int tilesx = W >> 4;
  const int ty0 = (blockIdx.x / tilesx) << 4, tx0 = (blockIdx.x % tilesx) << 4;
  const int co0 = (blockIdx.y >> 2) << 6;
  const int par = blockIdx.y & 3;
  const int pa = par >> 1, pb = par & 1;
  const int bb = blockIdx.z;
  const int t = threadIdx.x;
  const int lane = t & 63, wv = t >> 6;
  const int frow = lane & 15, kg = lane >> 4;
  __shared__ f16 at[256][40];
  __shared__ f16 btw[64][40];
  __shared__ float2 sred[4][64];
  f32x4 acc[4][4];
  #pragma unroll
  for (int i = 0; i < 4; ++i)
    #pragma unroll
    for (int j = 0; j < 4; ++j) acc[i][j] = (f32x4){0.f, 0.f, 0.f, 0.f};

  for (int c0 = 0; c0 < 256; c0 += 32) {
    __syncthreads();
    for (int i = t; i < 1024; i += 256) {
      const int cell = i >> 2, part = i & 3;
      const int gy = ty0 + (cell >> 4), gx = tx0 + (cell & 15);
      *(f16x8*)&at[cell][part * 8] =
          *(const f16x8*)&x[(((size_t)bb * H + gy) * W + gx) * 256 + c0 + part * 8];
    }
    {
      const int i = t;
      const int co = i >> 2, part = i & 3;
      *(f16x8*)&btw[co][part * 8] =
          *(const f16x8*)&wtp[((size_t)par * 256 + co0 + co) * 256 + c0 + part * 8];
    }
    __syncthreads();
    f16x8 af[4], bf[4];
    #pragma unroll
    for (int fm = 0; fm < 4; ++fm)
      af[fm] = *(const f16x8*)&at[wv * 64 + fm * 16 + frow][kg * 8];
    #pragma unroll
    for (int fn = 0; fn < 4; ++fn)
      bf[fn] = *(const f16x8*)&btw[fn * 16 + frow][kg * 8];
    #pragma unroll
    for (int fm = 0; fm < 4; ++fm)
      #pragma unroll
      for (int fn = 0; fn < 4; ++fn)
        acc[fm][fn] = __builtin_amdgcn_mfma_f32_16x16x32_f16(af[fm], bf[fn], acc[fm][fn], 0, 0, 0);
  }
  const int HO = H << 1, WO = W << 1;
  float ps[4] = {0.f, 0.f, 0.f, 0.f}, ss[4] = {0.f, 0.f, 0.f, 0.f};
  #pragma unroll
  for (int fn = 0; fn < 4; ++fn) {
    const int col = co0 + fn * 16 + frow;
    const float bv = bias[col];
    #pragma unroll
    for (int fm = 0; fm < 4; ++fm)
      #pragma unroll
      for (int r = 0; r < 4; ++r) {
        const int pos = wv * 64 + fm * 16 + kg * 4 + r;
        const int oy = ((ty0 + (pos >> 4)) << 1) + pa;
        const int ox = ((tx0 + (pos & 15)) << 1) + pb;
        const float v = acc[fm][fn][r] + bv;
        ps[fn] += v; ss[fn] += v * v;
        y[(((size_t)bb * HO + oy) * WO + ox) * 256 + col] = (f16)v;
      }
  }
  #pragma unroll
  for (int fn = 0; fn < 4; ++fn)
    #pragma unroll
    for (int msk = 16; msk < 64; msk <<= 1) {
      ps[fn] += __shfl_xor(ps[fn], msk);
      ss[fn] += __shfl_xor(ss[fn], msk);
    }
  __syncthreads();
  if (kg == 0) {
    #pragma unroll
    for (int fn = 0; fn < 4; ++fn) sred[wv][fn * 16 + frow] = make_float2(ps[fn], ss[fn]);
  }
  __syncthreads();
  if (t < 64) {
    float a1 = 0.f, a2 = 0.f;
    #pragma unroll
    for (int w = 0; w < 4; ++w) { a1 += sred[w][t].x; a2 += sred[w][t].y; }
    partial[((size_t)bb * 256 + blockIdx.x * 4 + par) * 256 + co0 + t] = make_float2(a1, a2);
  }
}

// ---------------------------------------------------------------- stats2 (runtime NS, parallel)
__global__ __launch_bounds__(256) void stats2v2_k(
    const float2* __restrict__ partial, float2* __restrict__ mr, int HW, int NS)
{
  const int cg = blockIdx.x, b = blockIdx.y, t = threadIdx.x;
  const int chl = t & 31, g = t >> 5;
  const int ch = cg * 32 + chl;
  float s1 = 0.f, s2 = 0.f;
  for (int s = g; s < NS; s += 8) {
    const float2 v = partial[((size_t)b * 256 + s) * 256 + ch];
    s1 += v.x; s2 += v.y;
  }
  __shared__ float r1[8][32], r2[8][32];
  r1[g][chl] = s1; r2[g][chl] = s2;
  __syncthreads();
  if (t < 32) {
    float a1 = 0.f, a2 = 0.f;
    #pragma unroll
    for (int gg = 0; gg < 8; ++gg) { a1 += r1[gg][t]; a2 += r2[gg][t]; }
    const float m = a1 / (float)HW;
    const float var = fmaxf(a2 / (float)HW - m * m, 0.f);
    mr[b * 256 + cg * 32 + t] = make_float2(m, rsqrtf(var + 1e-5f));
  }
}

// ---------------------------------------------------------------- vectorized normalize+leaky
__global__ __launch_bounds__(256) void norm8_k(
    f16* __restrict__ x, const float2* __restrict__ mr, int HW)
{
  const int b = blockIdx.y, t = threadIdx.x;
  const int cp = t & 31, rg = t >> 5;
  float2 mv[8];
  {
    const float2* mrb = mr + b * 256 + cp * 8;
    #pragma unroll
    for (int j = 0; j < 8; ++j) mv[j] = mrb[j];
  }
  f16* p = x + ((size_t)b * HW + (size_t)blockIdx.x * 64) * 256 + cp * 8;
  #pragma unroll
  for (int r8 = 0; r8 < 8; ++r8) {
    const int r = rg + r8 * 8;
    f16x8 v = *(const f16x8*)&p[(size_t)r * 256];
    #pragma unroll
    for (int j = 0; j < 8; ++j) {
      const float z = ((float)v[j] - mv[j].x) * mv[j].y;
      v[j] = (f16)(z >= 0.f ? z : 0.01f * z);
    }
    *(f16x8*)&p[(size_t)r * 256] = v;
  }
}

// ---------------------------------------------------------------- MFMA out conv 3x3; weights direct
__global__ __launch_bounds__(256) void convoutm2_k(
    const f16* __restrict__ x, const f16* __restrict__ wocp, const float* __restrict__ bias,
    void* __restrict__ yv, const int* __restrict__ flags)
{
  const int ty0 = (blockIdx.x >> 4) << 4, tx0 = (blockIdx.x & 15) << 4;
  const int b = blockIdx.y;
  const int t = threadIdx.x;
  const int lane = t & 63, wv = t >> 6;
  const int frow = lane & 15, kg = lane >> 4;
  __shared__ f16 halo[18][18][40];
  f32x4 acc[4];
  #pragma unroll
  for (int i = 0; i < 4; ++i) acc[i] = (f32x4){0.f, 0.f, 0.f, 0.f};

  for (int c0 = 0; c0 < 256; c0 += 32) {
    __syncthreads();
    for (int i = t; i < 1296; i += 256) {
      const int cell = i >> 2, part = i & 3;
      const int hy = cell / 18, hx = cell - hy * 18;
      const int gy = ty0 + hy - 1, gx = tx0 + hx - 1;
      f16x8 v = {(f16)0,(f16)0,(f16)0,(f16)0,(f16)0,(f16)0,(f16)0,(f16)0};
      if ((unsigned)gy < 256u && (unsigned)gx < 256u)
        v = *(const f16x8*)&x[(((size_t)b * 256 + gy) * 256 + gx) * 256 + c0 + part * 8];
      *(f16x8*)&halo[hy][hx][part * 8] = v;
    }
    __syncthreads();
    #pragma unroll
    for (int kyr = 0; kyr < 3; ++kyr)
      #pragma unroll
      for (int kx = 0; kx < 3; ++kx) {
        const int tap = kyr * 3 + kx;
        const f16x8 bf = *(const f16x8*)&wocp[((size_t)(tap * 16 + frow)) * 256 + c0 + kg * 8];
        #pragma unroll
        for (int fm = 0; fm < 4; ++fm) {
          const int pos = wv * 64 + fm * 16 + frow;
          const f16x8 af = *(const f16x8*)&halo[(pos >> 4) + kyr][(pos & 15) + kx][kg * 8];
          acc[fm] = __builtin_amdgcn_mfma_f32_16x16x32_f16(af, bf, acc[fm], 0, 0, 0);
        }
      }
  }
  if (frow < 3) {
    const int fp32 = flags[0];
    const float bv = bias[frow];
    #pragma unroll
    for (int fm = 0; fm < 4; ++fm)
      #pragma unroll
      for (int r = 0; r < 4; ++r) {
        const int pos = wv * 64 + fm * 16 + kg * 4 + r;
        const int oy = ty0 + (pos >> 4), ox = tx0 + (pos & 15);
        const size_t oidx = (((size_t)b * 3 + frow) * 256 + oy) * 256 + ox;
        const float v = acc[fm][r] + bv;
        if (fp32) ((float*)yv)[oidx] = v;
        else      ((bf16*)yv)[oidx] = __float2bfloat16(v);
      }
  }
}

// ================================================================ host
extern "C" void kernel_launch(void* const* d_in, const int* in_sizes, int n_in,
                              void* d_out, int out_size, void* d_ws, size_t ws_size,
                              hipStream_t stream) {
  (void)in_sizes; (void)n_in; (void)out_size; (void)ws_size;
  const int* pc = (const int*)d_in[1];

  float* P = (float*)d_ws;
  size_t off = 0;
  CvtDesc cd{};
  int seg = 0;
  auto alloc = [&](size_t n) { float* p = P + off; off += n; return p; };
  auto allocCv = [&](int idx, size_t n) {
    float* p = P + off;
    cd.src[seg] = d_in[idx]; cd.dstOff[seg] = (unsigned)off; cd.n[seg] = (unsigned)n;
    ++seg; off += n; return p;
  };

  // ---- persistent small region ----
  int*    flags   = (int*)alloc(16);
  int*    invbuf  = (int*)alloc(1024);
  float2* partial = (float2*)alloc(262144);
  float2* mr1     = (float2*)alloc(1024);
  float* pdb   = allocCv(3, 256);
  float* pw1   = allocCv(4, 512);
  float* pb1   = allocCv(5, 256);
  float* pb2   = allocCv(7, 256);
  float* pln1g = allocCv(9, 512);
  float* pln1b = allocCv(10, 512);
  float* pqkvb = allocCv(12, 1536);
  float* pattb = allocCv(14, 512);
  float* pln2g = allocCv(15, 512);
  float* pln2b = allocCv(16, 512);
  float* pm1b  = allocCv(18, 2048);
  float* pm2b  = allocCv(20, 512);
  float* pdecg = allocCv(21, 256);
  float* pdecb = allocCv(22, 256);
  float* pmg   = allocCv(25, 256);
  float* pmb   = allocCv(26, 256);
  float* pucb  = allocCv(28, 768);
  float* putb  = allocCv(30, 768);
  float* pocw  = allocCv(31, 6912);
  float* pocb  = allocCv(32, 16);
  off = (off + 255) & ~(size_t)255;
  f16* wf3  = (f16*)alloc(884736);
  f16* wt   = (f16*)alloc(393216);
  f16* wocp = (f16*)alloc(18432);
  off = (off + 255) & ~(size_t)255;

  // ---- zone A: big fp32 params + transformer scratch, later overlaid by R2 (f16) ----
  float* zoneA = P + off;
  f16*   R2h   = (f16*)zoneA;
  {
    size_t zo = off;
    auto zCv = [&](int idx, size_t n) {
      float* p = P + zo;
      cd.src[seg] = d_in[idx]; cd.dstOff[seg] = (unsigned)zo; cd.n[seg] = (unsigned)n;
      ++seg; zo += n; return p;
    };
    float* px    = zCv(0, 655360);
    float* pdw   = zCv(2, 131072);
    float* pw2   = zCv(6, 65536);
    float* pcls  = zCv(8, 65536);
    float* pqkvw = zCv(11, 393216);
    float* pattw = zCv(13, 131072);
    float* pm1w  = zCv(17, 524288);
    float* pm2w  = zCv(19, 524288);
    float* pprp  = zCv(23, 65536);
    float* pprc  = zCv(24, 65536);
    float* pucw  = zCv(27, 1769472);
    float* putw  = zCv(29, 786432);
    float* xbuf   = P + zo; zo += 458752;
    float* hbuf   = P + zo; zo += 458752;
    float* qkvbuf = P + zo; zo += 1376256;
    float* hidbuf = P + zo; zo += 1835008;
    float* posbuf = P + zo; zo += 163840;
    float* patbuf = P + zo; zo += 327680;
    float* clsbuf = P + zo; zo += 131072;
    float* masksb = P + zo; zo += 327680;
    off += 16777216;
    f16* R0h = (f16*)(P + off); off += 4194304;
    f16* R1h = (f16*)(P + off); off += 4194304;

    // 0) detect dtype, convert inputs to fp32, prep conv weights
    detect_k<<<1, 64, 0, stream>>>((const unsigned short*)d_in[0], flags);
    cvtall_k<<<dim3(256, NSEG), 256, 0, stream>>>(cd, P, flags);
    prepw_k<<<2048, 256, 0, stream>>>(pucw, putw, pocw, wf3, wt, wocp);

    // 1) positional MLP + projection + assembly
    posh_k<<<640, 256, 0, stream>>>(pc, pw1, pb1, patbuf);
    gemm64_k<false, 0><<<dim3(4, 10), 256, 0, stream>>>(
        patbuf, pw2, pb2, nullptr, posbuf, 640, 256, 256, 0, 0, 0);
    gemm64_k<false, 0><<<dim3(4, 20), 256, 0, stream>>>(
        px, pdw, pdb, nullptr, hidbuf, 1280, 256, 512, 0, 0, 0);
    assemble_k<<<1792, 256, 0, stream>>>(hidbuf, posbuf, pcls, xbuf);

    // 2) transformer blocks
    for (int l = 0; l < 2; ++l) {
      ln_k<<<1792, 256, 0, stream>>>(xbuf, hbuf, pln1g + l * 256, pln1b + l * 256);
      gemm64_k<false, 0><<<dim3(12, 28), 256, 0, stream>>>(
          hbuf, pqkvw + (size_t)l * 196608, pqkvb + l * 768, nullptr, qkvbuf, 1792, 768, 256, 0, 0, 0);
      attnm_k<<<dim3(28, 8, 2), 128, 0, stream>>>(qkvbuf, hbuf);
      gemm64_k<false, 0><<<dim3(4, 28), 256, 0, stream>>>(
          hbuf, pattw + (size_t)l * 65536, pattb + l * 256, xbuf, xbuf, 1792, 256, 256, 0, 0, 0);
      ln_k<<<1792, 256, 0, stream>>>(xbuf, hbuf, pln2g + l * 256, pln2b + l * 256);
      gemm64_k<false, 1><<<dim3(16, 28), 256, 0, stream>>>(
          hbuf, pm1w + (size_t)l * 262144, pm1b + l * 1024, nullptr, hidbuf, 1792, 1024, 256, 0, 0, 0);
      gemm64_k<false, 0><<<dim3(4, 28), 256, 0, stream>>>(
          hidbuf, pm2w + (size_t)l * 262144, pm2b + l * 256, xbuf, xbuf, 1792, 256, 1024, 0, 0, 0);
    }

    // 3) decoder head (batched over b via grid.z)
    ln_k<<<1792, 256, 0, stream>>>(xbuf, hbuf, pdecg, pdecb);
    gemm64_k<false, 0><<<dim3(4, 10, 2), 256, 0, stream>>>(
        hbuf, pprp, nullptr, nullptr, patbuf, 640, 256, 256,
        (size_t)896 * 256, 0, (size_t)640 * 256);
    gemm64_k<false, 0><<<dim3(4, 4, 2), 256, 0, stream>>>(
        hbuf + (size_t)640 * 256, pprc, nullptr, nullptr, clsbuf, 256, 256, 256,
        (size_t)896 * 256, 0, (size_t)65536);
    l2n_k<<<1280, 256, 0, stream>>>(patbuf);
    l2n_k<<<512, 256, 0, stream>>>(clsbuf);
    gemm64_k<true, 0><<<dim3(4, 10, 2), 256, 0, stream>>>(
        patbuf, clsbuf, nullptr, nullptr, masksb, 640, 256, 256,
        (size_t)163840, (size_t)65536, (size_t)163840);
    ln_k<<<1280, 256, 0, stream>>>(masksb, masksb, pmg, pmb);

    // 4) scatter table + gather
    inv_k<<<1, 1024, 0, stream>>>(pc, invbuf);
    gather16_k<<<2048, 256, 0, stream>>>(masksb, invbuf, R0h);

    // 5) MFMA conv decoder: fused stats epilogue + separate norm pass
    int H = 32;
    for (int i = 0; i < 3; ++i) {
      const int tiles = (H / 16) * (H / 16);
      conv3m_k<<<dim3(tiles, 4, 2), 256, 0, stream>>>(
          R0h, wf3 + (size_t)i * 9 * 65536, pucb + i * 256, R1h, H, H, partial);
      stats2v2_k<<<dim3(8, 2), 256, 0, stream>>>(partial, mr1, H * H, tiles);
      norm8_k<<<dim3(H * H / 64, 2), 256, 0, stream>>>(R1h, mr1, H * H);
      f16* dst = (i == 2) ? R2h : R0h;
      convtm_k<<<dim3(tiles, 16, 2), 256, 0, stream>>>(
          R1h, wt + (size_t)i * 4 * 65536, putb + i * 256, dst, H, H, partial);
      stats2v2_k<<<dim3(8, 2), 256, 0, stream>>>(partial, mr1, 4 * H * H, tiles * 4);
      norm8_k<<<dim3(4 * H * H / 64, 2), 256, 0, stream>>>(dst, mr1, 4 * H * H);
      H *= 2;
    }

    // 6) output conv 256 -> 3 via MFMA (reads pre-normalized R2)
    convoutm2_k<<<dim3(256, 2), 256, 0, stream>>>(R2h, wocp, pocb, d_out, flags);
  }
}